// Round 3
// baseline (7123.627 us; speedup 1.0000x reference)
//
#include <hip/hip_runtime.h>
#include <hip/hip_bf16.h>

// ---------------- problem constants ----------------
constexpr int Bn = 64;
constexpr int Tn = 512;
constexpr int Hn = 512;

using bf16x8 = __attribute__((ext_vector_type(8))) short;
using f32x4  = __attribute__((ext_vector_type(4))) float;

// ---------------- ws layout (byte offsets) ----------------
// A1: bf16 [2][64][512]   blended h1 state (ping-pong)
// A2: bf16 [2][64][1024]  cols 0..511 = nh1 (unblended), 512..1023 = blended h2 state
// BAR: barrier region (in old C1 area): slots[256] + flag  (zeroed by prep each call)
// BIASP: f32 [2][2048] gate-permuted biases
// H2ALL: f32 [64*512][512]  (m*nh2), head input; reused as X2
// X1: f32 region 64 MB (head intermediates); W/XPAD buffers overlap its start
constexpr size_t OFF_A1    = 0;
constexpr size_t OFF_A2    = OFF_A1 + (size_t)2*64*512*2;      // 131072
constexpr size_t OFF_C1    = OFF_A2 + (size_t)2*64*1024*2;     // 393216 (barrier area)
constexpr size_t OFF_C2    = OFF_C1 + (size_t)64*512*4;        // 524288 (unused)
constexpr size_t OFF_BIASP = OFF_C2 + (size_t)64*512*4;        // 655360
constexpr size_t OFF_H2ALL = OFF_BIASP + (size_t)2*2048*4;     // 671744
constexpr size_t OFF_X1    = OFF_H2ALL + (size_t)64*512*512*4; // 67780608
constexpr size_t OFF_XPAD  = OFF_X1;                            // bf16 [512][64][32] = 2 MB
constexpr size_t OFF_W1P   = OFF_XPAD + (size_t)512*64*32*2;    // bf16 [64][17][2][64][8]
constexpr size_t OFF_W2P   = OFF_W1P + (size_t)64*17*2*64*8*2;  // bf16 [64][32][2][64][8]
constexpr size_t WS_NEED   = OFF_X1 + (size_t)64*512*512*4;     // 134,889,472 B

__device__ __forceinline__ float sigf(float x) { return 1.f / (1.f + expf(-x)); }
__device__ __forceinline__ unsigned short f2b(float x) {
    __hip_bfloat16 h = __float2bfloat16(x);
    return *reinterpret_cast<unsigned short*>(&h);
}
__device__ __forceinline__ f32x4 mfma16(bf16x8 a, bf16x8 b, f32x4 c) {
    return __builtin_amdgcn_mfma_f32_16x16x32_bf16(a, b, c, 0, 0, 0);
}

// ---------------- one-time prep: swizzle W to MFMA frag order, pad x, zero state ----------------
constexpr int PN0 = 64*17*2*64;            // W1P ushort8 items   = 139264
constexpr int PN1 = PN0 + 64*32*2*64;      // W2P items           = 401408
constexpr int PN2 = PN1 + 4096;            // BIASP f32 items     = 405504
constexpr int PN3 = PN2 + 512*64*4;        // XPAD ushort8 items  = 536576
constexpr int PN4 = PN3 + 24576;           // zero A1+A2 ushort8  = 561152
constexpr int PN5 = PN4 + 16384;           // zero barrier area float4 = 577536

__global__ __launch_bounds__(256) void prep_kernel(
    const float* __restrict__ seq_in,
    const float* __restrict__ W1, const float* __restrict__ b1,
    const float* __restrict__ W2, const float* __restrict__ b2,
    char* __restrict__ ws)
{
    const int idx = blockIdx.x * 256 + threadIdx.x;
    if (idx >= PN5) return;
    if (idx < PN0) {                       // W1P
        const int lane = idx & 63; int r = idx >> 6;
        const int half = r & 1; r >>= 1;
        const int kk = r % 17, np = r / 17;
        const int colg = (np*2 + half)*16 + (lane & 15);
        const int oc = (colg & 3)*512 + (colg >> 2);
        const int lg = lane >> 4;
        short v[8];
        #pragma unroll
        for (int j = 0; j < 8; ++j) {
            float x;
            if (kk < 16) x = W1[(size_t)(6 + kk*32 + lg*8 + j) * 2048 + oc];
            else { const int rr = lg*8 + j; x = (rr < 6) ? W1[(size_t)rr * 2048 + oc] : 0.f; }
            v[j] = (short)f2b(x);
        }
        bf16x8* dst = (bf16x8*)((unsigned short*)(ws + OFF_W1P) + ((size_t)(np*17 + kk)*2 + half)*512 + lane*8);
        *dst = *(bf16x8*)v;
    } else if (idx < PN1) {                // W2P
        const int i = idx - PN0;
        const int lane = i & 63; int r = i >> 6;
        const int half = r & 1; r >>= 1;
        const int kk = r & 31, np = r >> 5;
        const int colg = (np*2 + half)*16 + (lane & 15);
        const int oc = (colg & 3)*512 + (colg >> 2);
        const int lg = lane >> 4;
        short v[8];
        #pragma unroll
        for (int j = 0; j < 8; ++j)
            v[j] = (short)f2b(W2[(size_t)(kk*32 + lg*8 + j) * 2048 + oc]);
        bf16x8* dst = (bf16x8*)((unsigned short*)(ws + OFF_W2P) + ((size_t)(np*32 + kk)*2 + half)*512 + lane*8);
        *dst = *(bf16x8*)v;
    } else if (idx < PN2) {                // BIASP
        const int i = idx - PN1;
        const int layer = i >> 11, colg = i & 2047;
        const float* bb = layer ? b2 : b1;
        ((float*)(ws + OFF_BIASP))[i] = bb[(colg & 3)*512 + (colg >> 2)];
    } else if (idx < PN3) {                // XPAD [t][b][32]
        const int i = idx - PN2;
        const int sub = i & 3, tb = i >> 2;
        const int t = tb >> 6, b = tb & 63;
        short v[8];
        #pragma unroll
        for (int j = 0; j < 8; ++j) {
            const int rr = sub*8 + j;
            v[j] = (short)f2b(rr < 6 ? seq_in[((size_t)b*Tn + t)*6 + rr] : 0.f);
        }
        bf16x8* dst = (bf16x8*)((unsigned short*)(ws + OFF_XPAD) + (size_t)tb*32 + sub*8);
        *dst = *(bf16x8*)v;
    } else if (idx < PN4) {                // zero A1 + A2
        const int i = idx - PN3;
        bf16x8 z = {};
        ((bf16x8*)((unsigned short*)(ws + OFF_A1)))[i] = z;
    } else {                               // zero barrier area (slots + flag)
        const int i = idx - PN4;
        ((float4*)(ws + OFF_C1))[i] = make_float4(0.f, 0.f, 0.f, 0.f);
    }
}

// ---------------- grid barrier (slot arrival + sweep + flag release) ----------------
__device__ __forceinline__ void gbar(int* slots, int* flagp, int tv)
{
    __syncthreads();                       // drains each wave's vmem stores (vmcnt 0 before s_barrier)
    if (threadIdx.x == 0) {
        __builtin_amdgcn_fence(__ATOMIC_RELEASE, "agent");   // L2 writeback (this XCD)
        __hip_atomic_store(&slots[blockIdx.x], tv, __ATOMIC_RELAXED, __HIP_MEMORY_SCOPE_AGENT);
    }
    if (blockIdx.x == 0 && threadIdx.x < 64) {
        const int i0 = (int)threadIdx.x * 4;
        for (;;) {
            int m0 = __hip_atomic_load(&slots[i0+0], __ATOMIC_RELAXED, __HIP_MEMORY_SCOPE_AGENT);
            int m1 = __hip_atomic_load(&slots[i0+1], __ATOMIC_RELAXED, __HIP_MEMORY_SCOPE_AGENT);
            int m2 = __hip_atomic_load(&slots[i0+2], __ATOMIC_RELAXED, __HIP_MEMORY_SCOPE_AGENT);
            int m3 = __hip_atomic_load(&slots[i0+3], __ATOMIC_RELAXED, __HIP_MEMORY_SCOPE_AGENT);
            int mn = min(min(m0, m1), min(m2, m3));
            if (__all(mn >= tv)) break;
            __builtin_amdgcn_s_sleep(1);
        }
        if (threadIdx.x == 0) {
            __builtin_amdgcn_fence(__ATOMIC_ACQUIRE, "agent");
            __hip_atomic_store(flagp, tv, __ATOMIC_RELEASE, __HIP_MEMORY_SCOPE_AGENT);
        }
    }
    if (threadIdx.x == 0) {
        while (__hip_atomic_load(flagp, __ATOMIC_RELAXED, __HIP_MEMORY_SCOPE_AGENT) < tv)
            __builtin_amdgcn_s_sleep(1);
        __builtin_amdgcn_fence(__ATOMIC_ACQUIRE, "agent");   // L2/L1 invalidate before next-step reads
    }
    __syncthreads();
}

// ---------------- persistent recurrence kernel ----------------
// 256 blocks x 256 threads (4 waves). Blocks 0..127: L1; 128..255: L2.
// Block vb: mt = vb>>5 (batch 16-row tile), waves cover nt = (vb&31)*4 + w (16-col tiles).
// Wave-private W in VGPRs; c/h-hold state in lane registers; one grid barrier per step.
constexpr int FRAGS = 520;   // ushort stride per kk slot (1040 B) - staggers bank classes

__global__ __launch_bounds__(256, 1) void persist_kernel(const int* __restrict__ lens,
                                                         char* __restrict__ ws)
{
    __shared__ unsigned short afrag[33 * FRAGS];
    __shared__ float sc[4][16][17];

    const int tid = threadIdx.x;
    const int l = tid & 63, w = tid >> 6;
    const int blk = blockIdx.x;
    const bool isL1 = (blk < 128);
    const int vb = isL1 ? blk : blk - 128;
    const int mt = vb >> 5;
    const int nt = (vb & 31) * 4 + w;
    const int np = nt >> 1, half = nt & 1;
    const int lr = l & 15, lg = l >> 4;

    unsigned short* A1 = (unsigned short*)(ws + OFF_A1);
    unsigned short* A2 = (unsigned short*)(ws + OFF_A2);
    int* slots = (int*)(ws + OFF_C1);
    int* flagp = slots + 256;
    const float* biasp = (const float*)(ws + OFF_BIASP);
    float* h2all = (float*)(ws + OFF_H2ALL);
    const unsigned short* XP = (const unsigned short*)(ws + OFF_XPAD);

    // ---- load private W slice into registers ----
    bf16x8 wreg[32];
    if (isL1) {
        const unsigned short* Bp = (const unsigned short*)(ws + OFF_W1P)
                                 + ((size_t)(np*17)*2 + half)*512 + l*8;
        #pragma unroll
        for (int kk = 0; kk < 17; ++kk) wreg[kk] = *(const bf16x8*)(Bp + (size_t)kk*1024);
    } else {
        const unsigned short* Bp = (const unsigned short*)(ws + OFF_W2P)
                                 + ((size_t)(np*32)*2 + half)*512 + l*8;
        #pragma unroll
        for (int kk = 0; kk < 32; ++kk) wreg[kk] = *(const bf16x8*)(Bp + (size_t)kk*1024);
    }

    const int myb = mt*16 + lr;            // owned batch row
    const int myd = nt*4 + lg;             // owned h-dim
    const int mylen = lens[myb];
    const float biascol = biasp[(isL1 ? 0 : 2048) + nt*16 + lr];  // bias of this lane's C column
    float c_reg = 0.f, h_reg = 0.f;

    for (int t = 0; t <= Tn; ++t) {
        const bool active = isL1 ? (t < Tn) : (t >= 1);
        if (active) {
            const int s = t - 1;
            // ---- stage A tile into LDS in fragment order ----
            if (isL1) {
                const unsigned short* src = A1 + (size_t)((t+1)&1)*(64*512);
                #pragma unroll
                for (int it = 0; it < 4; ++it) {
                    const int q = tid + it*256;
                    const int r = q >> 6, g = q & 63;
                    bf16x8 v = *(const bf16x8*)(src + (size_t)(mt*16 + r)*512 + g*8);
                    *(bf16x8*)(afrag + (g>>2)*FRAGS + ((g&3)*16 + r)*8) = v;
                }
                if (tid < 64) {
                    const int r = tid >> 2, lgg = tid & 3;
                    bf16x8 v = *(const bf16x8*)(XP + ((size_t)t*64 + mt*16 + r)*32 + lgg*8);
                    *(bf16x8*)(afrag + 16*FRAGS + (lgg*16 + r)*8) = v;
                }
            } else {
                const unsigned short* src = A2 + (size_t)(s&1)*(64*1024);
                #pragma unroll
                for (int it = 0; it < 8; ++it) {
                    const int q = tid + it*256;
                    const int r = q >> 7, g = q & 127;
                    bf16x8 v = *(const bf16x8*)(src + (size_t)(mt*16 + r)*1024 + g*8);
                    *(bf16x8*)(afrag + (g>>2)*FRAGS + ((g&3)*16 + r)*8) = v;
                }
            }
            __syncthreads();

            // ---- MFMA over K ----
            f32x4 acc = {0.f, 0.f, 0.f, 0.f};
            const unsigned short* ap = afrag + l*8;
            if (isL1) {
                #pragma unroll
                for (int kk = 0; kk < 17; ++kk)
                    acc = mfma16(*(const bf16x8*)(ap + kk*FRAGS), wreg[kk], acc);
            } else {
                #pragma unroll
                for (int kk = 0; kk < 32; ++kk)
                    acc = mfma16(*(const bf16x8*)(ap + kk*FRAGS), wreg[kk], acc);
            }

            // ---- wave-local gate exchange ----
            #pragma unroll
            for (int i = 0; i < 4; ++i)
                sc[w][lg*4 + i][lr] = acc[i] + biascol;
            asm volatile("s_waitcnt lgkmcnt(0)" ::: "memory");

            const float gi = sc[w][lr][lg*4 + 0];
            const float gj = sc[w][lr][lg*4 + 1];
            const float gf = sc[w][lr][lg*4 + 2];
            const float go = sc[w][lr][lg*4 + 3];

            const int stepidx = isL1 ? t : s;
            const float m = (stepidx < mylen) ? 1.f : 0.f;
            const float sgf = sigf(gf + 1.f), sgi = sigf(gi), sgo = sigf(go);
            const float tj = tanhf(gj);
            const float cnew = c_reg*sgf + sgi*tj;
            c_reg = m*cnew + (1.f - m)*c_reg;
            const float nh = tanhf(cnew)*sgo;
            const float hb = m*nh + (1.f - m)*h_reg;
            h_reg = hb;

            if (isL1) {
                A2[(size_t)(t&1)*(64*1024) + (size_t)myb*1024 + myd] = f2b(nh);
                A1[(size_t)(t&1)*(64*512)  + (size_t)myb*512  + myd] = f2b(hb);
            } else {
                A2[(size_t)(t&1)*(64*1024) + (size_t)myb*1024 + 512 + myd] = f2b(hb);
                h2all[((size_t)myb*Tn + s)*512 + myd] = m*nh;
            }
        }
        if (t < Tn) gbar(slots, flagp, t + 1);
    }
}

// ---------------- dense GEMM: C = relu?(A[M,K] @ W[K,N] + bias) (f32, validated) ----------------
__global__ __launch_bounds__(256) void gemm_relu_kernel(
    const float* __restrict__ A, const float* __restrict__ W,
    const float* __restrict__ bias, float* __restrict__ C,
    int M, int N, int K, int relu)
{
    __shared__ float As[16][132];
    __shared__ float Bs[16][128];
    const int tid = threadIdx.x;
    const int tx = tid & 15, ty = tid >> 4;
    const int rbase = blockIdx.y * 128, cbase = blockIdx.x * 128;

    float acc[8][8] = {};
    for (int k0 = 0; k0 < K; k0 += 16) {
        #pragma unroll
        for (int u = 0; u < 2; ++u) {
            const int idx4 = u * 256 + tid;
            const int kk4 = idx4 & 3, rr = idx4 >> 2;
            const float4 v = *reinterpret_cast<const float4*>(
                A + (size_t)(rbase + rr) * K + k0 + kk4 * 4);
            As[kk4 * 4 + 0][rr] = v.x; As[kk4 * 4 + 1][rr] = v.y;
            As[kk4 * 4 + 2][rr] = v.z; As[kk4 * 4 + 3][rr] = v.w;
        }
        #pragma unroll
        for (int u = 0; u < 2; ++u) {
            const int idx4 = u * 256 + tid;
            const int cc4 = idx4 & 31, kk = idx4 >> 5;
            *reinterpret_cast<float4*>(&Bs[kk][cc4 * 4]) =
                *reinterpret_cast<const float4*>(W + (size_t)(k0 + kk) * N + cbase + cc4 * 4);
        }
        __syncthreads();
        #pragma unroll
        for (int kk = 0; kk < 16; ++kk) {
            const float4 A0 = *reinterpret_cast<const float4*>(&As[kk][ty * 8]);
            const float4 A1 = *reinterpret_cast<const float4*>(&As[kk][ty * 8 + 4]);
            const float4 B0 = *reinterpret_cast<const float4*>(&Bs[kk][tx * 8]);
            const float4 B1 = *reinterpret_cast<const float4*>(&Bs[kk][tx * 8 + 4]);
            const float av[8] = {A0.x, A0.y, A0.z, A0.w, A1.x, A1.y, A1.z, A1.w};
            const float bv[8] = {B0.x, B0.y, B0.z, B0.w, B1.x, B1.y, B1.z, B1.w};
            #pragma unroll
            for (int i = 0; i < 8; ++i)
                #pragma unroll
                for (int j = 0; j < 8; ++j) acc[i][j] += av[i] * bv[j];
        }
        __syncthreads();
    }
    float bvs[8];
    #pragma unroll
    for (int j = 0; j < 8; ++j) bvs[j] = bias[cbase + tx * 8 + j];
    #pragma unroll
    for (int i = 0; i < 8; ++i) {
        const int r = rbase + ty * 8 + i;
        float o[8];
        #pragma unroll
        for (int j = 0; j < 8; ++j) {
            float v = acc[i][j] + bvs[j];
            o[j] = relu ? fmaxf(v, 0.f) : v;
        }
        float4* p = reinterpret_cast<float4*>(C + (size_t)r * N + cbase + tx * 8);
        p[0] = make_float4(o[0], o[1], o[2], o[3]);
        p[1] = make_float4(o[4], o[5], o[6], o[7]);
    }
}

// ---------------- final tiny layer ----------------
__global__ __launch_bounds__(256) void d4_kernel(
    const float* __restrict__ X3, const float* __restrict__ W,
    const float* __restrict__ bias, float* __restrict__ out)
{
    const int lane = threadIdx.x & 63;
    const int rr = threadIdx.x >> 6;
    const size_t r = (size_t)blockIdx.x * 4 + rr;
    float p0 = 0, p1 = 0, p2 = 0, p3 = 0;
    #pragma unroll
    for (int j = 0; j < 4; ++j) {
        const int k = j * 64 + lane;
        const float x = X3[r * 256 + k];
        const float4 w = *reinterpret_cast<const float4*>(W + (size_t)k * 4);
        p0 += x * w.x; p1 += x * w.y; p2 += x * w.z; p3 += x * w.w;
    }
    #pragma unroll
    for (int off = 32; off > 0; off >>= 1) {
        p0 += __shfl_down(p0, off); p1 += __shfl_down(p1, off);
        p2 += __shfl_down(p2, off); p3 += __shfl_down(p3, off);
    }
    if (lane == 0) {
        *reinterpret_cast<float4*>(out + r * 4) =
            make_float4(p0 + bias[0], p1 + bias[1], p2 + bias[2], p3 + bias[3]);
    }
}

// ---------------- masked sequence MSE ----------------
__global__ __launch_bounds__(256) void loss_kernel(
    const float* __restrict__ out, const float* __restrict__ tgt,
    const int* __restrict__ lens, float* __restrict__ lossp)
{
    __shared__ float red[256];
    float acc = 0.f;
    for (int idx = threadIdx.x; idx < Bn * Tn; idx += 256) {
        const int b = idx >> 9;  // T = 512
        const float4 o = *reinterpret_cast<const float4*>(out + (size_t)idx * 4);
        const float4 g = *reinterpret_cast<const float4*>(tgt + (size_t)idx * 4);
        const float dx = o.x - g.x, dy = o.y - g.y, dz = o.z - g.z, dw = o.w - g.w;
        const float fm = 0.25f * (dx * dx + dy * dy + dz * dz + dw * dw);
        const float ma = fmaxf(fmaxf(fabsf(g.x), fabsf(g.y)), fmaxf(fabsf(g.z), fabsf(g.w)));
        const float mask = (ma > 0.f) ? 1.f : 0.f;
        acc += fm * mask / ((float)lens[b] * 64.f);
    }
    red[threadIdx.x] = acc;
    __syncthreads();
    for (int st = 128; st > 0; st >>= 1) {
        if (threadIdx.x < st) red[threadIdx.x] += red[threadIdx.x + st];
        __syncthreads();
    }
    if (threadIdx.x == 0) *lossp = red[0];
}

__global__ void sentinel_kernel(float* __restrict__ out, int n)
{
    for (int i = blockIdx.x * 256 + threadIdx.x; i < n; i += gridDim.x * 256)
        out[i] = 1.0e9f;
}

extern "C" void kernel_launch(void* const* d_in, const int* in_sizes, int n_in,
                              void* d_out, int out_size, void* d_ws, size_t ws_size,
                              hipStream_t stream)
{
    const float* seq_in = (const float*)d_in[0];
    const float* tgt    = (const float*)d_in[1];
    const int*   lens   = (const int*)d_in[2];
    const float* W1  = (const float*)d_in[3];
    const float* b1  = (const float*)d_in[4];
    const float* W2  = (const float*)d_in[5];
    const float* b2  = (const float*)d_in[6];
    const float* Wd1 = (const float*)d_in[7];
    const float* bd1 = (const float*)d_in[8];
    const float* Wd2 = (const float*)d_in[9];
    const float* bd2 = (const float*)d_in[10];
    const float* Wd3 = (const float*)d_in[11];
    const float* bd3 = (const float*)d_in[12];
    const float* Wd4 = (const float*)d_in[13];
    const float* bd4 = (const float*)d_in[14];
    float* out = (float*)d_out;
    char* ws = (char*)d_ws;

    if (ws_size < WS_NEED) {
        hipLaunchKernelGGL(sentinel_kernel, dim3(256), dim3(256), 0, stream, out, out_size);
        return;
    }

    hipLaunchKernelGGL(prep_kernel, dim3((PN5 + 255) / 256), dim3(256), 0, stream,
                       seq_in, W1, b1, W2, b2, ws);

    hipLaunchKernelGGL(persist_kernel, dim3(256), dim3(256), 0, stream, lens, ws);

    float* h2all = (float*)(ws + OFF_H2ALL);
    float* X1    = (float*)(ws + OFF_X1);
    float* X2 = h2all;   // h2all dead after D1
    float* X3 = X1;      // X1 dead after D2

    hipLaunchKernelGGL(gemm_relu_kernel, dim3(4, 256), dim3(256), 0, stream,
                       h2all, Wd1, bd1, X1, Bn * Tn, 512, 512, 1);
    hipLaunchKernelGGL(gemm_relu_kernel, dim3(4, 256), dim3(256), 0, stream,
                       X1, Wd2, bd2, X2, Bn * Tn, 512, 512, 1);
    hipLaunchKernelGGL(gemm_relu_kernel, dim3(2, 256), dim3(256), 0, stream,
                       X2, Wd3, bd3, X3, Bn * Tn, 256, 512, 1);
    hipLaunchKernelGGL(d4_kernel, dim3((Bn * Tn) / 4), dim3(256), 0, stream,
                       X3, Wd4, bd4, out);
    hipLaunchKernelGGL(loss_kernel, dim3(1), dim3(256), 0, stream,
                       out, tgt, lens, out + (size_t)Bn * Tn * 4);
}

// Round 4
// 3959.346 us; speedup vs baseline: 1.7992x; 1.7992x over previous
//
#include <hip/hip_runtime.h>
#include <hip/hip_bf16.h>

// ---------------- problem constants ----------------
constexpr int Bn = 64;
constexpr int Tn = 512;
constexpr int Hn = 512;

using bf16x8 = __attribute__((ext_vector_type(8))) short;
using f32x4  = __attribute__((ext_vector_type(4))) float;
typedef unsigned long long u64;

// ---------------- ws layout (byte offsets) ----------------
constexpr size_t OFF_A1    = 0;                                 // bf16 [2][64][512] blended h1
constexpr size_t OFF_A2    = OFF_A1 + (size_t)2*64*512*2;       // bf16 [2][64][1024] nh1|h2
constexpr size_t OFF_C1    = OFF_A2 + (size_t)2*64*1024*2;      // barrier slots/flag region
constexpr size_t OFF_C2    = OFF_C1 + (size_t)64*512*4;
constexpr size_t OFF_BIASP = OFF_C2 + (size_t)64*512*4;         // f32 [2][2048] permuted biases
constexpr size_t OFF_H2ALL = OFF_BIASP + (size_t)2*2048*4;      // f32 [B*T][512]
constexpr size_t OFF_X1    = OFF_H2ALL + (size_t)64*512*512*4;
constexpr size_t OFF_XPAD  = OFF_X1;                            // bf16 [512][64][32]
constexpr size_t OFF_W1P   = OFF_XPAD + (size_t)512*64*32*2;    // bf16 [64][17][2][64][8]
constexpr size_t OFF_W2P   = OFF_W1P + (size_t)64*17*2*64*8*2;  // bf16 [64][32][2][64][8]
constexpr size_t WS_NEED   = OFF_X1 + (size_t)64*512*512*4;

__device__ __forceinline__ float sigf(float x) { return 1.f / (1.f + expf(-x)); }
__device__ __forceinline__ unsigned short f2b(float x) {
    __hip_bfloat16 h = __float2bfloat16(x);
    return *reinterpret_cast<unsigned short*>(&h);
}
__device__ __forceinline__ f32x4 mfma16(bf16x8 a, bf16x8 b, f32x4 c) {
    return __builtin_amdgcn_mfma_f32_16x16x32_bf16(a, b, c, 0, 0, 0);
}

// agent-scope relaxed atomics: sc-bit loads/stores that bypass stale per-XCD
// caches and hit the coherence point (IF) WITHOUT any cache-wide fence/flush.
__device__ __forceinline__ u64 ld_agent_u64(const u64* p) {
    return __hip_atomic_load(p, __ATOMIC_RELAXED, __HIP_MEMORY_SCOPE_AGENT);
}
__device__ __forceinline__ void st_agent_u64(u64* p, u64 v) {
    __hip_atomic_store(p, v, __ATOMIC_RELAXED, __HIP_MEMORY_SCOPE_AGENT);
}
__device__ __forceinline__ int ld_agent_i32(const int* p) {
    return __hip_atomic_load(p, __ATOMIC_RELAXED, __HIP_MEMORY_SCOPE_AGENT);
}
__device__ __forceinline__ void st_agent_i32(int* p, int v) {
    __hip_atomic_store(p, v, __ATOMIC_RELAXED, __HIP_MEMORY_SCOPE_AGENT);
}

// ---------------- one-time prep ----------------
constexpr int PN0 = 64*17*2*64;
constexpr int PN1 = PN0 + 64*32*2*64;
constexpr int PN2 = PN1 + 4096;
constexpr int PN3 = PN2 + 512*64*4;
constexpr int PN4 = PN3 + 24576;
constexpr int PN5 = PN4 + 16384;

__global__ __launch_bounds__(256) void prep_kernel(
    const float* __restrict__ seq_in,
    const float* __restrict__ W1, const float* __restrict__ b1,
    const float* __restrict__ W2, const float* __restrict__ b2,
    char* __restrict__ ws)
{
    const int idx = blockIdx.x * 256 + threadIdx.x;
    if (idx >= PN5) return;
    if (idx < PN0) {                       // W1P
        const int lane = idx & 63; int r = idx >> 6;
        const int half = r & 1; r >>= 1;
        const int kk = r % 17, np = r / 17;
        const int colg = (np*2 + half)*16 + (lane & 15);
        const int oc = (colg & 3)*512 + (colg >> 2);
        const int lg = lane >> 4;
        short v[8];
        #pragma unroll
        for (int j = 0; j < 8; ++j) {
            float x;
            if (kk < 16) x = W1[(size_t)(6 + kk*32 + lg*8 + j) * 2048 + oc];
            else { const int rr = lg*8 + j; x = (rr < 6) ? W1[(size_t)rr * 2048 + oc] : 0.f; }
            v[j] = (short)f2b(x);
        }
        bf16x8* dst = (bf16x8*)((unsigned short*)(ws + OFF_W1P) + ((size_t)(np*17 + kk)*2 + half)*512 + lane*8);
        *dst = *(bf16x8*)v;
    } else if (idx < PN1) {                // W2P
        const int i = idx - PN0;
        const int lane = i & 63; int r = i >> 6;
        const int half = r & 1; r >>= 1;
        const int kk = r & 31, np = r >> 5;
        const int colg = (np*2 + half)*16 + (lane & 15);
        const int oc = (colg & 3)*512 + (colg >> 2);
        const int lg = lane >> 4;
        short v[8];
        #pragma unroll
        for (int j = 0; j < 8; ++j)
            v[j] = (short)f2b(W2[(size_t)(kk*32 + lg*8 + j) * 2048 + oc]);
        bf16x8* dst = (bf16x8*)((unsigned short*)(ws + OFF_W2P) + ((size_t)(np*32 + kk)*2 + half)*512 + lane*8);
        *dst = *(bf16x8*)v;
    } else if (idx < PN2) {                // BIASP
        const int i = idx - PN1;
        const int layer = i >> 11, colg = i & 2047;
        const float* bb = layer ? b2 : b1;
        ((float*)(ws + OFF_BIASP))[i] = bb[(colg & 3)*512 + (colg >> 2)];
    } else if (idx < PN3) {                // XPAD [t][b][32]
        const int i = idx - PN2;
        const int sub = i & 3, tb = i >> 2;
        const int t = tb >> 6, b = tb & 63;
        short v[8];
        #pragma unroll
        for (int j = 0; j < 8; ++j) {
            const int rr = sub*8 + j;
            v[j] = (short)f2b(rr < 6 ? seq_in[((size_t)b*Tn + t)*6 + rr] : 0.f);
        }
        bf16x8* dst = (bf16x8*)((unsigned short*)(ws + OFF_XPAD) + (size_t)tb*32 + sub*8);
        *dst = *(bf16x8*)v;
    } else if (idx < PN4) {                // zero A1 + A2
        const int i = idx - PN3;
        bf16x8 z = {};
        ((bf16x8*)((unsigned short*)(ws + OFF_A1)))[i] = z;
    } else {                               // zero barrier area (slots + flag)
        const int i = idx - PN4;
        ((float4*)(ws + OFF_C1))[i] = make_float4(0.f, 0.f, 0.f, 0.f);
    }
}

// ---------------- fence-free grid barrier ----------------
// __syncthreads drains every wave's vmcnt (sc-stores complete at IF) before
// the arrival store. No agent fences => no L2 writeback/invalidate per step.
__device__ __forceinline__ void gbar(int* slots, int* flagp, int tv)
{
    __syncthreads();
    if (threadIdx.x == 0)
        st_agent_i32(&slots[blockIdx.x], tv);
    if (blockIdx.x == 0 && threadIdx.x < 64) {
        const int i0 = (int)threadIdx.x * 4;
        for (;;) {
            int m0 = ld_agent_i32(&slots[i0+0]);
            int m1 = ld_agent_i32(&slots[i0+1]);
            int m2 = ld_agent_i32(&slots[i0+2]);
            int m3 = ld_agent_i32(&slots[i0+3]);
            if (__all(min(min(m0, m1), min(m2, m3)) >= tv)) break;
            __builtin_amdgcn_s_sleep(2);
        }
        if (threadIdx.x == 0) st_agent_i32(flagp, tv);
    }
    if (threadIdx.x == 0) {
        while (ld_agent_i32(flagp) < tv) __builtin_amdgcn_s_sleep(2);
    }
    __syncthreads();
}

// ---------------- persistent recurrence kernel ----------------
constexpr int FRAGS = 520;   // ushort stride per kk slot (1040 B)

__global__ __launch_bounds__(256, 1) void persist_kernel(const int* __restrict__ lens,
                                                         char* __restrict__ ws)
{
    __shared__ unsigned short afrag[33 * FRAGS];
    __shared__ float sc[4][16][17];

    const int tid = threadIdx.x;
    const int l = tid & 63, w = tid >> 6;
    const int blk = blockIdx.x;
    const bool isL1 = (blk < 128);
    const int vb = isL1 ? blk : blk - 128;
    const int mt = vb >> 5;
    const int nt = (vb & 31) * 4 + w;
    const int np = nt >> 1, half = nt & 1;
    const int lr = l & 15, lg = l >> 4;

    unsigned short* A1 = (unsigned short*)(ws + OFF_A1);
    unsigned short* A2 = (unsigned short*)(ws + OFF_A2);
    int* slots = (int*)(ws + OFF_C1);
    int* flagp = slots + 512;
    const float* biasp = (const float*)(ws + OFF_BIASP);
    float* h2all = (float*)(ws + OFF_H2ALL);
    const unsigned short* XP = (const unsigned short*)(ws + OFF_XPAD);

    // ---- private W slice in VGPRs for all 512 steps ----
    bf16x8 wreg[32];
    if (isL1) {
        const unsigned short* Bp = (const unsigned short*)(ws + OFF_W1P)
                                 + ((size_t)(np*17)*2 + half)*512 + l*8;
        #pragma unroll
        for (int kk = 0; kk < 17; ++kk) wreg[kk] = *(const bf16x8*)(Bp + (size_t)kk*1024);
    } else {
        const unsigned short* Bp = (const unsigned short*)(ws + OFF_W2P)
                                 + ((size_t)(np*32)*2 + half)*512 + l*8;
        #pragma unroll
        for (int kk = 0; kk < 32; ++kk) wreg[kk] = *(const bf16x8*)(Bp + (size_t)kk*1024);
    }

    const int myb = mt*16 + lr;
    const int myd = nt*4 + lg;
    const int mylen = lens[myb];
    const float biascol = biasp[(isL1 ? 0 : 2048) + nt*16 + lr];
    float c_reg = 0.f, h_reg = 0.f;

    for (int t = 0; t <= Tn; ++t) {
        const bool active = isL1 ? (t < Tn) : (t >= 1);
        if (active) {
            const int s = t - 1;
            // ---- stage A tile into LDS (agent u64 loads -> frag order) ----
            if (isL1) {
                const u64* srcu = (const u64*)(A1 + (size_t)((t+1)&1)*(64*512));
                #pragma unroll
                for (int it = 0; it < 8; ++it) {
                    const int idx = tid + it*256;
                    const int r = idx >> 7, g4 = idx & 127;
                    u64 v = ld_agent_u64(srcu + (size_t)(mt*16 + r)*128 + g4);
                    const int off = (g4>>3)*FRAGS + (((g4>>1)&3)*16 + r)*8 + (g4&1)*4;
                    *(u64*)(afrag + off) = v;
                }
                if (tid < 64) {
                    const int r = tid >> 2, lgg = tid & 3;
                    bf16x8 v = *(const bf16x8*)(XP + ((size_t)t*64 + mt*16 + r)*32 + lgg*8);
                    *(bf16x8*)(afrag + 16*FRAGS + (lgg*16 + r)*8) = v;
                }
            } else {
                const u64* srcu = (const u64*)(A2 + (size_t)(s&1)*(64*1024));
                #pragma unroll
                for (int it = 0; it < 16; ++it) {
                    const int idx = tid + it*256;
                    const int r = idx >> 8, g4 = idx & 255;
                    u64 v = ld_agent_u64(srcu + (size_t)(mt*16 + r)*256 + g4);
                    const int off = (g4>>3)*FRAGS + (((g4>>1)&3)*16 + r)*8 + (g4&1)*4;
                    *(u64*)(afrag + off) = v;
                }
            }
            __syncthreads();

            // ---- MFMA over K ----
            f32x4 acc = {0.f, 0.f, 0.f, 0.f};
            const unsigned short* ap = afrag + l*8;
            if (isL1) {
                #pragma unroll
                for (int kk = 0; kk < 17; ++kk)
                    acc = mfma16(*(const bf16x8*)(ap + kk*FRAGS), wreg[kk], acc);
            } else {
                #pragma unroll
                for (int kk = 0; kk < 32; ++kk)
                    acc = mfma16(*(const bf16x8*)(ap + kk*FRAGS), wreg[kk], acc);
            }

            // ---- wave-local gate exchange ----
            #pragma unroll
            for (int i = 0; i < 4; ++i)
                sc[w][lg*4 + i][lr] = acc[i] + biascol;
            asm volatile("s_waitcnt lgkmcnt(0)" ::: "memory");

            const float gi = sc[w][lr][lg*4 + 0];
            const float gj = sc[w][lr][lg*4 + 1];
            const float gf = sc[w][lr][lg*4 + 2];
            const float go = sc[w][lr][lg*4 + 3];

            const int stepidx = isL1 ? t : s;
            const float m = (stepidx < mylen) ? 1.f : 0.f;
            const float sgf = sigf(gf + 1.f), sgi = sigf(gi), sgo = sigf(go);
            const float tj = tanhf(gj);
            const float cnew = c_reg*sgf + sgi*tj;
            c_reg = m*cnew + (1.f - m)*c_reg;
            const float nh = tanhf(cnew)*sgo;
            const float hb = m*nh + (1.f - m)*h_reg;
            h_reg = hb;

            // ---- shuffle-pack 4 lanes -> u64, agent store ----
            const int sv = ((int)f2b(hb) << 16) | (int)f2b(nh);
            const int g0 = __shfl(sv, lr +  0);
            const int g1 = __shfl(sv, lr + 16);
            const int g2 = __shfl(sv, lr + 32);
            const int g3 = __shfl(sv, lr + 48);
            if (isL1) {
                if (lg == 0) {
                    u64 nhp = (u64)(unsigned)((g0 & 0xffff) | ((g1 & 0xffff) << 16))
                            | ((u64)(unsigned)((g2 & 0xffff) | ((g3 & 0xffff) << 16)) << 32);
                    u64 hbp = (u64)(((unsigned)g0 >> 16) | (((unsigned)g1 >> 16) << 16))
                            | ((u64)(((unsigned)g2 >> 16) | (((unsigned)g3 >> 16) << 16)) << 32);
                    u64* A2u = (u64*)(A2 + (size_t)(t&1)*(64*1024));
                    u64* A1u = (u64*)(A1 + (size_t)(t&1)*(64*512));
                    st_agent_u64(A2u + (size_t)myb*256 + nt, nhp);        // nh1 -> L2 input
                    st_agent_u64(A1u + (size_t)myb*128 + nt, hbp);        // blended h1
                }
            } else {
                if (lg == 0) {
                    u64 hbp = (u64)(((unsigned)g0 >> 16) | (((unsigned)g1 >> 16) << 16))
                            | ((u64)(((unsigned)g2 >> 16) | (((unsigned)g3 >> 16) << 16)) << 32);
                    u64* A2u = (u64*)(A2 + (size_t)(t&1)*(64*1024));
                    st_agent_u64(A2u + (size_t)myb*256 + 128 + nt, hbp);  // blended h2
                }
                h2all[((size_t)myb*Tn + s)*512 + myd] = m*nh;             // normal cached store
            }
        }
        if (t < Tn) gbar(slots, flagp, t + 1);
    }
}

// ---------------- dense GEMM: C = relu?(A[M,K] @ W[K,N] + bias) ----------------
__global__ __launch_bounds__(256) void gemm_relu_kernel(
    const float* __restrict__ A, const float* __restrict__ W,
    const float* __restrict__ bias, float* __restrict__ C,
    int M, int N, int K, int relu)
{
    __shared__ float As[16][132];
    __shared__ float Bs[16][128];
    const int tid = threadIdx.x;
    const int tx = tid & 15, ty = tid >> 4;
    const int rbase = blockIdx.y * 128, cbase = blockIdx.x * 128;

    float acc[8][8] = {};
    for (int k0 = 0; k0 < K; k0 += 16) {
        #pragma unroll
        for (int u = 0; u < 2; ++u) {
            const int idx4 = u * 256 + tid;
            const int kk4 = idx4 & 3, rr = idx4 >> 2;
            const float4 v = *reinterpret_cast<const float4*>(
                A + (size_t)(rbase + rr) * K + k0 + kk4 * 4);
            As[kk4 * 4 + 0][rr] = v.x; As[kk4 * 4 + 1][rr] = v.y;
            As[kk4 * 4 + 2][rr] = v.z; As[kk4 * 4 + 3][rr] = v.w;
        }
        #pragma unroll
        for (int u = 0; u < 2; ++u) {
            const int idx4 = u * 256 + tid;
            const int cc4 = idx4 & 31, kk = idx4 >> 5;
            *reinterpret_cast<float4*>(&Bs[kk][cc4 * 4]) =
                *reinterpret_cast<const float4*>(W + (size_t)(k0 + kk) * N + cbase + cc4 * 4);
        }
        __syncthreads();
        #pragma unroll
        for (int kk = 0; kk < 16; ++kk) {
            const float4 A0 = *reinterpret_cast<const float4*>(&As[kk][ty * 8]);
            const float4 A1 = *reinterpret_cast<const float4*>(&As[kk][ty * 8 + 4]);
            const float4 B0 = *reinterpret_cast<const float4*>(&Bs[kk][tx * 8]);
            const float4 B1 = *reinterpret_cast<const float4*>(&Bs[kk][tx * 8 + 4]);
            const float av[8] = {A0.x, A0.y, A0.z, A0.w, A1.x, A1.y, A1.z, A1.w};
            const float bv[8] = {B0.x, B0.y, B0.z, B0.w, B1.x, B1.y, B1.z, B1.w};
            #pragma unroll
            for (int i = 0; i < 8; ++i)
                #pragma unroll
                for (int j = 0; j < 8; ++j) acc[i][j] += av[i] * bv[j];
        }
        __syncthreads();
    }
    float bvs[8];
    #pragma unroll
    for (int j = 0; j < 8; ++j) bvs[j] = bias[cbase + tx * 8 + j];
    #pragma unroll
    for (int i = 0; i < 8; ++i) {
        const int r = rbase + ty * 8 + i;
        float o[8];
        #pragma unroll
        for (int j = 0; j < 8; ++j) {
            float v = acc[i][j] + bvs[j];
            o[j] = relu ? fmaxf(v, 0.f) : v;
        }
        float4* p = reinterpret_cast<float4*>(C + (size_t)r * N + cbase + tx * 8);
        p[0] = make_float4(o[0], o[1], o[2], o[3]);
        p[1] = make_float4(o[4], o[5], o[6], o[7]);
    }
}

// ---------------- final tiny layer ----------------
__global__ __launch_bounds__(256) void d4_kernel(
    const float* __restrict__ X3, const float* __restrict__ W,
    const float* __restrict__ bias, float* __restrict__ out)
{
    const int lane = threadIdx.x & 63;
    const int rr = threadIdx.x >> 6;
    const size_t r = (size_t)blockIdx.x * 4 + rr;
    float p0 = 0, p1 = 0, p2 = 0, p3 = 0;
    #pragma unroll
    for (int j = 0; j < 4; ++j) {
        const int k = j * 64 + lane;
        const float x = X3[r * 256 + k];
        const float4 w = *reinterpret_cast<const float4*>(W + (size_t)k * 4);
        p0 += x * w.x; p1 += x * w.y; p2 += x * w.z; p3 += x * w.w;
    }
    #pragma unroll
    for (int off = 32; off > 0; off >>= 1) {
        p0 += __shfl_down(p0, off); p1 += __shfl_down(p1, off);
        p2 += __shfl_down(p2, off); p3 += __shfl_down(p3, off);
    }
    if (lane == 0) {
        *reinterpret_cast<float4*>(out + r * 4) =
            make_float4(p0 + bias[0], p1 + bias[1], p2 + bias[2], p3 + bias[3]);
    }
}

// ---------------- masked sequence MSE ----------------
__global__ __launch_bounds__(256) void loss_kernel(
    const float* __restrict__ out, const float* __restrict__ tgt,
    const int* __restrict__ lens, float* __restrict__ lossp)
{
    __shared__ float red[256];
    float acc = 0.f;
    for (int idx = threadIdx.x; idx < Bn * Tn; idx += 256) {
        const int b = idx >> 9;
        const float4 o = *reinterpret_cast<const float4*>(out + (size_t)idx * 4);
        const float4 g = *reinterpret_cast<const float4*>(tgt + (size_t)idx * 4);
        const float dx = o.x - g.x, dy = o.y - g.y, dz = o.z - g.z, dw = o.w - g.w;
        const float fm = 0.25f * (dx * dx + dy * dy + dz * dz + dw * dw);
        const float ma = fmaxf(fmaxf(fabsf(g.x), fabsf(g.y)), fmaxf(fabsf(g.z), fabsf(g.w)));
        const float mask = (ma > 0.f) ? 1.f : 0.f;
        acc += fm * mask / ((float)lens[b] * 64.f);
    }
    red[threadIdx.x] = acc;
    __syncthreads();
    for (int st = 128; st > 0; st >>= 1) {
        if (threadIdx.x < st) red[threadIdx.x] += red[threadIdx.x + st];
        __syncthreads();
    }
    if (threadIdx.x == 0) *lossp = red[0];
}

__global__ void sentinel_kernel(float* __restrict__ out, int n)
{
    for (int i = blockIdx.x * 256 + threadIdx.x; i < n; i += gridDim.x * 256)
        out[i] = 1.0e9f;
}

extern "C" void kernel_launch(void* const* d_in, const int* in_sizes, int n_in,
                              void* d_out, int out_size, void* d_ws, size_t ws_size,
                              hipStream_t stream)
{
    const float* seq_in = (const float*)d_in[0];
    const float* tgt    = (const float*)d_in[1];
    const int*   lens   = (const int*)d_in[2];
    const float* W1  = (const float*)d_in[3];
    const float* b1  = (const float*)d_in[4];
    const float* W2  = (const float*)d_in[5];
    const float* b2  = (const float*)d_in[6];
    const float* Wd1 = (const float*)d_in[7];
    const float* bd1 = (const float*)d_in[8];
    const float* Wd2 = (const float*)d_in[9];
    const float* bd2 = (const float*)d_in[10];
    const float* Wd3 = (const float*)d_in[11];
    const float* bd3 = (const float*)d_in[12];
    const float* Wd4 = (const float*)d_in[13];
    const float* bd4 = (const float*)d_in[14];
    float* out = (float*)d_out;
    char* ws = (char*)d_ws;

    if (ws_size < WS_NEED) {
        hipLaunchKernelGGL(sentinel_kernel, dim3(256), dim3(256), 0, stream, out, out_size);
        return;
    }

    hipLaunchKernelGGL(prep_kernel, dim3((PN5 + 255) / 256), dim3(256), 0, stream,
                       seq_in, W1, b1, W2, b2, ws);

    hipLaunchKernelGGL(persist_kernel, dim3(256), dim3(256), 0, stream, lens, ws);

    float* h2all = (float*)(ws + OFF_H2ALL);
    float* X1    = (float*)(ws + OFF_X1);
    float* X2 = h2all;
    float* X3 = X1;

    hipLaunchKernelGGL(gemm_relu_kernel, dim3(4, 256), dim3(256), 0, stream,
                       h2all, Wd1, bd1, X1, Bn * Tn, 512, 512, 1);
    hipLaunchKernelGGL(gemm_relu_kernel, dim3(4, 256), dim3(256), 0, stream,
                       X1, Wd2, bd2, X2, Bn * Tn, 512, 512, 1);
    hipLaunchKernelGGL(gemm_relu_kernel, dim3(2, 256), dim3(256), 0, stream,
                       X2, Wd3, bd3, X3, Bn * Tn, 256, 512, 1);
    hipLaunchKernelGGL(d4_kernel, dim3((Bn * Tn) / 4), dim3(256), 0, stream,
                       X3, Wd4, bd4, out);
    hipLaunchKernelGGL(loss_kernel, dim3(1), dim3(256), 0, stream,
                       out, tgt, lens, out + (size_t)Bn * Tn * 4);
}

// Round 5
// 3423.211 us; speedup vs baseline: 2.0810x; 1.1566x over previous
//
#include <hip/hip_runtime.h>
#include <hip/hip_bf16.h>

// ---------------- problem constants ----------------
constexpr int Bn = 64;
constexpr int Tn = 512;
constexpr int Hn = 512;

using bf16x8 = __attribute__((ext_vector_type(8))) short;
using f32x4  = __attribute__((ext_vector_type(4))) float;
typedef unsigned long long u64;

// ---------------- ws layout (byte offsets) ----------------
constexpr size_t OFF_A1    = 0;                                 // bf16 [2][64][512] blended h1
constexpr size_t OFF_A2    = OFF_A1 + (size_t)2*64*512*2;       // bf16 [2][64][1024] nh1|h2
constexpr size_t OFF_C1    = OFF_A2 + (size_t)2*64*1024*2;      // barrier slots region
constexpr size_t OFF_C2    = OFF_C1 + (size_t)64*512*4;
constexpr size_t OFF_BIASP = OFF_C2 + (size_t)64*512*4;         // f32 [2][2048] permuted biases
constexpr size_t OFF_H2ALL = OFF_BIASP + (size_t)2*2048*4;      // f32 [B*T][512]
constexpr size_t OFF_X1    = OFF_H2ALL + (size_t)64*512*512*4;
constexpr size_t OFF_XPAD  = OFF_X1;                            // bf16 [512][64][32]
constexpr size_t OFF_W1P   = OFF_XPAD + (size_t)512*64*32*2;    // bf16 [64][17][2][64][8]
constexpr size_t OFF_W2P   = OFF_W1P + (size_t)64*17*2*64*8*2;  // bf16 [64][32][2][64][8]
constexpr size_t WS_NEED   = OFF_X1 + (size_t)64*512*512*4;

__device__ __forceinline__ float sigf(float x) { return 1.f / (1.f + expf(-x)); }
__device__ __forceinline__ unsigned short f2b(float x) {
    __hip_bfloat16 h = __float2bfloat16(x);
    return *reinterpret_cast<unsigned short*>(&h);
}
__device__ __forceinline__ f32x4 mfma16(bf16x8 a, bf16x8 b, f32x4 c) {
    return __builtin_amdgcn_mfma_f32_16x16x32_bf16(a, b, c, 0, 0, 0);
}

// agent-scope relaxed atomics: coherence-point accesses, no cache-wide fences
__device__ __forceinline__ u64 ld_agent_u64(const u64* p) {
    return __hip_atomic_load(p, __ATOMIC_RELAXED, __HIP_MEMORY_SCOPE_AGENT);
}
__device__ __forceinline__ void st_agent_u64(u64* p, u64 v) {
    __hip_atomic_store(p, v, __ATOMIC_RELAXED, __HIP_MEMORY_SCOPE_AGENT);
}
__device__ __forceinline__ int ld_agent_i32(const int* p) {
    return __hip_atomic_load(p, __ATOMIC_RELAXED, __HIP_MEMORY_SCOPE_AGENT);
}
__device__ __forceinline__ void st_agent_i32(int* p, int v) {
    __hip_atomic_store(p, v, __ATOMIC_RELAXED, __HIP_MEMORY_SCOPE_AGENT);
}

// ---------------- one-time prep ----------------
constexpr int PN0 = 64*17*2*64;
constexpr int PN1 = PN0 + 64*32*2*64;
constexpr int PN2 = PN1 + 4096;
constexpr int PN3 = PN2 + 512*64*4;
constexpr int PN4 = PN3 + 24576;
constexpr int PN5 = PN4 + 16384;

__global__ __launch_bounds__(256) void prep_kernel(
    const float* __restrict__ seq_in,
    const float* __restrict__ W1, const float* __restrict__ b1,
    const float* __restrict__ W2, const float* __restrict__ b2,
    char* __restrict__ ws)
{
    const int idx = blockIdx.x * 256 + threadIdx.x;
    if (idx >= PN5) return;
    if (idx < PN0) {                       // W1P
        const int lane = idx & 63; int r = idx >> 6;
        const int half = r & 1; r >>= 1;
        const int kk = r % 17, np = r / 17;
        const int colg = (np*2 + half)*16 + (lane & 15);
        const int oc = (colg & 3)*512 + (colg >> 2);
        const int lg = lane >> 4;
        short v[8];
        #pragma unroll
        for (int j = 0; j < 8; ++j) {
            float x;
            if (kk < 16) x = W1[(size_t)(6 + kk*32 + lg*8 + j) * 2048 + oc];
            else { const int rr = lg*8 + j; x = (rr < 6) ? W1[(size_t)rr * 2048 + oc] : 0.f; }
            v[j] = (short)f2b(x);
        }
        bf16x8* dst = (bf16x8*)((unsigned short*)(ws + OFF_W1P) + ((size_t)(np*17 + kk)*2 + half)*512 + lane*8);
        *dst = *(bf16x8*)v;
    } else if (idx < PN1) {                // W2P
        const int i = idx - PN0;
        const int lane = i & 63; int r = i >> 6;
        const int half = r & 1; r >>= 1;
        const int kk = r & 31, np = r >> 5;
        const int colg = (np*2 + half)*16 + (lane & 15);
        const int oc = (colg & 3)*512 + (colg >> 2);
        const int lg = lane >> 4;
        short v[8];
        #pragma unroll
        for (int j = 0; j < 8; ++j)
            v[j] = (short)f2b(W2[(size_t)(kk*32 + lg*8 + j) * 2048 + oc]);
        bf16x8* dst = (bf16x8*)((unsigned short*)(ws + OFF_W2P) + ((size_t)(np*32 + kk)*2 + half)*512 + lane*8);
        *dst = *(bf16x8*)v;
    } else if (idx < PN2) {                // BIASP
        const int i = idx - PN1;
        const int layer = i >> 11, colg = i & 2047;
        const float* bb = layer ? b2 : b1;
        ((float*)(ws + OFF_BIASP))[i] = bb[(colg & 3)*512 + (colg >> 2)];
    } else if (idx < PN3) {                // XPAD [t][b][32]
        const int i = idx - PN2;
        const int sub = i & 3, tb = i >> 2;
        const int t = tb >> 6, b = tb & 63;
        short v[8];
        #pragma unroll
        for (int j = 0; j < 8; ++j) {
            const int rr = sub*8 + j;
            v[j] = (short)f2b(rr < 6 ? seq_in[((size_t)b*Tn + t)*6 + rr] : 0.f);
        }
        bf16x8* dst = (bf16x8*)((unsigned short*)(ws + OFF_XPAD) + (size_t)tb*32 + sub*8);
        *dst = *(bf16x8*)v;
    } else if (idx < PN4) {                // zero A1 + A2
        const int i = idx - PN3;
        bf16x8 z = {};
        ((bf16x8*)((unsigned short*)(ws + OFF_A1)))[i] = z;
    } else {                               // zero barrier area (slots)
        const int i = idx - PN4;
        ((float4*)(ws + OFF_C1))[i] = make_float4(0.f, 0.f, 0.f, 0.f);
    }
}

// ---------------- persistent recurrence kernel ----------------
// 128 blocks x 512 threads (8 waves). Blocks 0..63: L1; 64..127: L2.
// vb = blk (L1) / blk-64 (L2); mt = vb>>4 (batch 16-row group); ng = vb&15.
// Wave w handles col-tile nt = ng*8 + w (16 gate-cols).
// Sync: per-mt-group barrier over 32 blocks (16 L1 + 16 L2) — direct all-poll,
// no central sweeper/flag. Groups advance independently (batch rows are
// independent; all dataflow stays within an mt group).
constexpr int FRAGS = 520;   // ushort stride per kk slot (1040 B)

__global__ __launch_bounds__(512, 2) void persist_kernel(const int* __restrict__ lens,
                                                         char* __restrict__ ws)
{
    __shared__ unsigned short afrag[33 * FRAGS];
    __shared__ float sc[8][16][17];

    const int tid = threadIdx.x;
    const int l = tid & 63, w = tid >> 6;
    const int blk = blockIdx.x;
    const bool isL1 = (blk < 64);
    const int vb = isL1 ? blk : blk - 64;
    const int mt = vb >> 4;
    const int ng = vb & 15;
    const int nt = ng * 8 + w;
    const int np = nt >> 1, half = nt & 1;
    const int lr = l & 15, lg = l >> 4;

    unsigned short* A1 = (unsigned short*)(ws + OFF_A1);
    unsigned short* A2 = (unsigned short*)(ws + OFF_A2);
    int* slots = (int*)(ws + OFF_C1);                 // [4 groups][64-int region]
    const int sidx = mt*64 + (isL1 ? 0 : 16) + ng;    // this block's slot
    const float* biasp = (const float*)(ws + OFF_BIASP);
    float* h2all = (float*)(ws + OFF_H2ALL);
    const unsigned short* XP = (const unsigned short*)(ws + OFF_XPAD);

    // ---- private W slice in VGPRs for all 512 steps ----
    bf16x8 wreg[32];
    if (isL1) {
        const unsigned short* Bp = (const unsigned short*)(ws + OFF_W1P)
                                 + ((size_t)(np*17)*2 + half)*512 + l*8;
        #pragma unroll
        for (int kk = 0; kk < 17; ++kk) wreg[kk] = *(const bf16x8*)(Bp + (size_t)kk*1024);
    } else {
        const unsigned short* Bp = (const unsigned short*)(ws + OFF_W2P)
                                 + ((size_t)(np*32)*2 + half)*512 + l*8;
        #pragma unroll
        for (int kk = 0; kk < 32; ++kk) wreg[kk] = *(const bf16x8*)(Bp + (size_t)kk*1024);
    }

    const int myb = mt*16 + lr;
    const int myd = nt*4 + lg;
    const int mylen = lens[myb];
    const float biascol = biasp[(isL1 ? 0 : 2048) + nt*16 + lr];
    float c_reg = 0.f, h_reg = 0.f;

    for (int t = 0; t <= Tn; ++t) {
        const bool active = isL1 ? (t < Tn) : (t >= 1);
        if (active) {
            const int s = t - 1;
            // ---- stage A tile into LDS (agent u64 loads -> frag order) ----
            if (isL1) {
                const u64* srcu = (const u64*)(A1 + (size_t)((t+1)&1)*(64*512));
                #pragma unroll
                for (int it = 0; it < 4; ++it) {
                    const int idx = tid + it*512;
                    const int r = idx >> 7, g4 = idx & 127;
                    u64 v = ld_agent_u64(srcu + (size_t)(mt*16 + r)*128 + g4);
                    const int off = (g4>>3)*FRAGS + (((g4>>1)&3)*16 + r)*8 + (g4&1)*4;
                    *(u64*)(afrag + off) = v;
                }
                if (tid < 64) {
                    const int r = tid >> 2, lgg = tid & 3;
                    bf16x8 v = *(const bf16x8*)(XP + ((size_t)t*64 + mt*16 + r)*32 + lgg*8);
                    *(bf16x8*)(afrag + 16*FRAGS + (lgg*16 + r)*8) = v;
                }
            } else {
                const u64* srcu = (const u64*)(A2 + (size_t)(s&1)*(64*1024));
                #pragma unroll
                for (int it = 0; it < 8; ++it) {
                    const int idx = tid + it*512;
                    const int r = idx >> 8, g4 = idx & 255;
                    u64 v = ld_agent_u64(srcu + (size_t)(mt*16 + r)*256 + g4);
                    const int off = (g4>>3)*FRAGS + (((g4>>1)&3)*16 + r)*8 + (g4&1)*4;
                    *(u64*)(afrag + off) = v;
                }
            }
            __syncthreads();

            // ---- MFMA over K ----
            f32x4 acc = {0.f, 0.f, 0.f, 0.f};
            const unsigned short* ap = afrag + l*8;
            if (isL1) {
                #pragma unroll
                for (int kk = 0; kk < 17; ++kk)
                    acc = mfma16(*(const bf16x8*)(ap + kk*FRAGS), wreg[kk], acc);
            } else {
                #pragma unroll
                for (int kk = 0; kk < 32; ++kk)
                    acc = mfma16(*(const bf16x8*)(ap + kk*FRAGS), wreg[kk], acc);
            }

            // ---- wave-local gate exchange ----
            #pragma unroll
            for (int i = 0; i < 4; ++i)
                sc[w][lg*4 + i][lr] = acc[i] + biascol;
            asm volatile("s_waitcnt lgkmcnt(0)" ::: "memory");

            const float gi = sc[w][lr][lg*4 + 0];
            const float gj = sc[w][lr][lg*4 + 1];
            const float gf = sc[w][lr][lg*4 + 2];
            const float go = sc[w][lr][lg*4 + 3];

            const int stepidx = isL1 ? t : s;
            const float m = (stepidx < mylen) ? 1.f : 0.f;
            const float sgf = sigf(gf + 1.f), sgi = sigf(gi), sgo = sigf(go);
            const float tj = tanhf(gj);
            const float cnew = c_reg*sgf + sgi*tj;
            c_reg = m*cnew + (1.f - m)*c_reg;
            const float nh = tanhf(cnew)*sgo;
            const float hb = m*nh + (1.f - m)*h_reg;
            h_reg = hb;

            // ---- shuffle-pack 4 lanes -> u64, agent store ----
            const int sv = ((int)f2b(hb) << 16) | (int)f2b(nh);
            const int g0 = __shfl(sv, lr +  0);
            const int g1 = __shfl(sv, lr + 16);
            const int g2 = __shfl(sv, lr + 32);
            const int g3 = __shfl(sv, lr + 48);
            if (isL1) {
                if (lg == 0) {
                    u64 nhp = (u64)(unsigned)((g0 & 0xffff) | ((g1 & 0xffff) << 16))
                            | ((u64)(unsigned)((g2 & 0xffff) | ((g3 & 0xffff) << 16)) << 32);
                    u64 hbp = (u64)(((unsigned)g0 >> 16) | (((unsigned)g1 >> 16) << 16))
                            | ((u64)(((unsigned)g2 >> 16) | (((unsigned)g3 >> 16) << 16)) << 32);
                    u64* A2u = (u64*)(A2 + (size_t)(t&1)*(64*1024));
                    u64* A1u = (u64*)(A1 + (size_t)(t&1)*(64*512));
                    st_agent_u64(A2u + (size_t)myb*256 + nt, nhp);        // nh1 -> L2 input
                    st_agent_u64(A1u + (size_t)myb*128 + nt, hbp);        // blended h1
                }
            } else {
                if (lg == 0) {
                    u64 hbp = (u64)(((unsigned)g0 >> 16) | (((unsigned)g1 >> 16) << 16))
                            | ((u64)(((unsigned)g2 >> 16) | (((unsigned)g3 >> 16) << 16)) << 32);
                    u64* A2u = (u64*)(A2 + (size_t)(t&1)*(64*1024));
                    st_agent_u64(A2u + (size_t)myb*256 + 128 + nt, hbp);  // blended h2
                }
                h2all[((size_t)myb*Tn + s)*512 + myd] = m*nh;             // cached store
            }
        }
        // ---- per-group barrier: arrive + direct all-poll (2 IF legs) ----
        if (t < Tn) {
            const int tv = t + 1;
            __syncthreads();                       // drain all waves' stores
            if (tid == 0) st_agent_i32(&slots[sidx], tv);
            if (tid < 64) {
                int v;
                do {
                    v = (tid < 32) ? ld_agent_i32(&slots[mt*64 + tid]) : tv;
                } while (!__all(v >= tv));
            }
            __syncthreads();
        }
    }
}

// ---------------- dense GEMM: C = relu?(A[M,K] @ W[K,N] + bias) ----------------
__global__ __launch_bounds__(256) void gemm_relu_kernel(
    const float* __restrict__ A, const float* __restrict__ W,
    const float* __restrict__ bias, float* __restrict__ C,
    int M, int N, int K, int relu)
{
    __shared__ float As[16][132];
    __shared__ float Bs[16][128];
    const int tid = threadIdx.x;
    const int tx = tid & 15, ty = tid >> 4;
    const int rbase = blockIdx.y * 128, cbase = blockIdx.x * 128;

    float acc[8][8] = {};
    for (int k0 = 0; k0 < K; k0 += 16) {
        #pragma unroll
        for (int u = 0; u < 2; ++u) {
            const int idx4 = u * 256 + tid;
            const int kk4 = idx4 & 3, rr = idx4 >> 2;
            const float4 v = *reinterpret_cast<const float4*>(
                A + (size_t)(rbase + rr) * K + k0 + kk4 * 4);
            As[kk4 * 4 + 0][rr] = v.x; As[kk4 * 4 + 1][rr] = v.y;
            As[kk4 * 4 + 2][rr] = v.z; As[kk4 * 4 + 3][rr] = v.w;
        }
        #pragma unroll
        for (int u = 0; u < 2; ++u) {
            const int idx4 = u * 256 + tid;
            const int cc4 = idx4 & 31, kk = idx4 >> 5;
            *reinterpret_cast<float4*>(&Bs[kk][cc4 * 4]) =
                *reinterpret_cast<const float4*>(W + (size_t)(k0 + kk) * N + cbase + cc4 * 4);
        }
        __syncthreads();
        #pragma unroll
        for (int kk = 0; kk < 16; ++kk) {
            const float4 A0 = *reinterpret_cast<const float4*>(&As[kk][ty * 8]);
            const float4 A1 = *reinterpret_cast<const float4*>(&As[kk][ty * 8 + 4]);
            const float4 B0 = *reinterpret_cast<const float4*>(&Bs[kk][tx * 8]);
            const float4 B1 = *reinterpret_cast<const float4*>(&Bs[kk][tx * 8 + 4]);
            const float av[8] = {A0.x, A0.y, A0.z, A0.w, A1.x, A1.y, A1.z, A1.w};
            const float bv[8] = {B0.x, B0.y, B0.z, B0.w, B1.x, B1.y, B1.z, B1.w};
            #pragma unroll
            for (int i = 0; i < 8; ++i)
                #pragma unroll
                for (int j = 0; j < 8; ++j) acc[i][j] += av[i] * bv[j];
        }
        __syncthreads();
    }
    float bvs[8];
    #pragma unroll
    for (int j = 0; j < 8; ++j) bvs[j] = bias[cbase + tx * 8 + j];
    #pragma unroll
    for (int i = 0; i < 8; ++i) {
        const int r = rbase + ty * 8 + i;
        float o[8];
        #pragma unroll
        for (int j = 0; j < 8; ++j) {
            float v = acc[i][j] + bvs[j];
            o[j] = relu ? fmaxf(v, 0.f) : v;
        }
        float4* p = reinterpret_cast<float4*>(C + (size_t)r * N + cbase + tx * 8);
        p[0] = make_float4(o[0], o[1], o[2], o[3]);
        p[1] = make_float4(o[4], o[5], o[6], o[7]);
    }
}

// ---------------- final tiny layer ----------------
__global__ __launch_bounds__(256) void d4_kernel(
    const float* __restrict__ X3, const float* __restrict__ W,
    const float* __restrict__ bias, float* __restrict__ out)
{
    const int lane = threadIdx.x & 63;
    const int rr = threadIdx.x >> 6;
    const size_t r = (size_t)blockIdx.x * 4 + rr;
    float p0 = 0, p1 = 0, p2 = 0, p3 = 0;
    #pragma unroll
    for (int j = 0; j < 4; ++j) {
        const int k = j * 64 + lane;
        const float x = X3[r * 256 + k];
        const float4 w = *reinterpret_cast<const float4*>(W + (size_t)k * 4);
        p0 += x * w.x; p1 += x * w.y; p2 += x * w.z; p3 += x * w.w;
    }
    #pragma unroll
    for (int off = 32; off > 0; off >>= 1) {
        p0 += __shfl_down(p0, off); p1 += __shfl_down(p1, off);
        p2 += __shfl_down(p2, off); p3 += __shfl_down(p3, off);
    }
    if (lane == 0) {
        *reinterpret_cast<float4*>(out + r * 4) =
            make_float4(p0 + bias[0], p1 + bias[1], p2 + bias[2], p3 + bias[3]);
    }
}

// ---------------- masked sequence MSE ----------------
__global__ __launch_bounds__(256) void loss_kernel(
    const float* __restrict__ out, const float* __restrict__ tgt,
    const int* __restrict__ lens, float* __restrict__ lossp)
{
    __shared__ float red[256];
    float acc = 0.f;
    for (int idx = threadIdx.x; idx < Bn * Tn; idx += 256) {
        const int b = idx >> 9;
        const float4 o = *reinterpret_cast<const float4*>(out + (size_t)idx * 4);
        const float4 g = *reinterpret_cast<const float4*>(tgt + (size_t)idx * 4);
        const float dx = o.x - g.x, dy = o.y - g.y, dz = o.z - g.z, dw = o.w - g.w;
        const float fm = 0.25f * (dx * dx + dy * dy + dz * dz + dw * dw);
        const float ma = fmaxf(fmaxf(fabsf(g.x), fabsf(g.y)), fmaxf(fabsf(g.z), fabsf(g.w)));
        const float mask = (ma > 0.f) ? 1.f : 0.f;
        acc += fm * mask / ((float)lens[b] * 64.f);
    }
    red[threadIdx.x] = acc;
    __syncthreads();
    for (int st = 128; st > 0; st >>= 1) {
        if (threadIdx.x < st) red[threadIdx.x] += red[threadIdx.x + st];
        __syncthreads();
    }
    if (threadIdx.x == 0) *lossp = red[0];
}

__global__ void sentinel_kernel(float* __restrict__ out, int n)
{
    for (int i = blockIdx.x * 256 + threadIdx.x; i < n; i += gridDim.x * 256)
        out[i] = 1.0e9f;
}

extern "C" void kernel_launch(void* const* d_in, const int* in_sizes, int n_in,
                              void* d_out, int out_size, void* d_ws, size_t ws_size,
                              hipStream_t stream)
{
    const float* seq_in = (const float*)d_in[0];
    const float* tgt    = (const float*)d_in[1];
    const int*   lens   = (const int*)d_in[2];
    const float* W1  = (const float*)d_in[3];
    const float* b1  = (const float*)d_in[4];
    const float* W2  = (const float*)d_in[5];
    const float* b2  = (const float*)d_in[6];
    const float* Wd1 = (const float*)d_in[7];
    const float* bd1 = (const float*)d_in[8];
    const float* Wd2 = (const float*)d_in[9];
    const float* bd2 = (const float*)d_in[10];
    const float* Wd3 = (const float*)d_in[11];
    const float* bd3 = (const float*)d_in[12];
    const float* Wd4 = (const float*)d_in[13];
    const float* bd4 = (const float*)d_in[14];
    float* out = (float*)d_out;
    char* ws = (char*)d_ws;

    if (ws_size < WS_NEED) {
        hipLaunchKernelGGL(sentinel_kernel, dim3(256), dim3(256), 0, stream, out, out_size);
        return;
    }

    hipLaunchKernelGGL(prep_kernel, dim3((PN5 + 255) / 256), dim3(256), 0, stream,
                       seq_in, W1, b1, W2, b2, ws);

    hipLaunchKernelGGL(persist_kernel, dim3(128), dim3(512), 0, stream, lens, ws);

    float* h2all = (float*)(ws + OFF_H2ALL);
    float* X1    = (float*)(ws + OFF_X1);
    float* X2 = h2all;
    float* X3 = X1;

    hipLaunchKernelGGL(gemm_relu_kernel, dim3(4, 256), dim3(256), 0, stream,
                       h2all, Wd1, bd1, X1, Bn * Tn, 512, 512, 1);
    hipLaunchKernelGGL(gemm_relu_kernel, dim3(4, 256), dim3(256), 0, stream,
                       X1, Wd2, bd2, X2, Bn * Tn, 512, 512, 1);
    hipLaunchKernelGGL(gemm_relu_kernel, dim3(2, 256), dim3(256), 0, stream,
                       X2, Wd3, bd3, X3, Bn * Tn, 256, 512, 1);
    hipLaunchKernelGGL(d4_kernel, dim3((Bn * Tn) / 4), dim3(256), 0, stream,
                       X3, Wd4, bd4, out);
    hipLaunchKernelGGL(loss_kernel, dim3(1), dim3(256), 0, stream,
                       out, tgt, lens, out + (size_t)Bn * Tn * 4);
}

// Round 7
// 3296.951 us; speedup vs baseline: 2.1607x; 1.0383x over previous
//
#include <hip/hip_runtime.h>
#include <hip/hip_bf16.h>

// ---------------- problem constants ----------------
constexpr int Bn = 64;
constexpr int Tn = 512;

using bf16x8 = __attribute__((ext_vector_type(8))) short;
using f32x4  = __attribute__((ext_vector_type(4))) float;
typedef unsigned long long u64;

// ---------------- ws layout (byte offsets) ----------------
constexpr size_t OFF_A1    = 0;                       // bf16 [2][64][512] blended h1
constexpr size_t OFF_AN    = OFF_A1  + 131072;        // bf16 [3][64][512] nh1 (3-deep)
constexpr size_t OFF_A2S   = OFF_AN  + 196608;        // bf16 [2][64][512] blended h2
constexpr size_t OFF_BAR   = OFF_A2S + 131072;        // 4 groups x 64 ints (slotsL1|slotsL2)
constexpr size_t OFF_BIASP = OFF_BAR + 4096;          // f32 [2][2048] permuted biases
constexpr size_t OFF_H2ALL = OFF_BIASP + 16384;       // bf16 [32768][512]
constexpr size_t OFF_X1    = OFF_H2ALL + 33554432;    // bf16 [32768][512]
constexpr size_t OFF_XPAD  = OFF_X1 + 33554432;       // bf16 [512][64][32]
constexpr size_t OFF_W1P   = OFF_XPAD + 2097152;      // bf16 [64][17][2][64][8]
constexpr size_t OFF_W2P   = OFF_W1P + 2228224;       // bf16 [64][32][2][64][8]
constexpr size_t OFF_WD1P  = OFF_W2P + 4194304;       // bf16 [32][16][64][8]
constexpr size_t OFF_WD2P  = OFF_WD1P + 524288;       // bf16 [32][16][64][8]
constexpr size_t OFF_WD3P  = OFF_WD2P + 524288;       // bf16 [16][16][64][8]
constexpr size_t WS_NEED   = OFF_WD3P + 262144;       // ~77.4 MB

__device__ __forceinline__ float sigf(float x) { return 1.f / (1.f + expf(-x)); }
__device__ __forceinline__ unsigned short f2b(float x) {
    __hip_bfloat16 h = __float2bfloat16(x);
    return *reinterpret_cast<unsigned short*>(&h);
}
__device__ __forceinline__ float b2f(unsigned short u) {
    unsigned v = ((unsigned)u) << 16;
    return *reinterpret_cast<float*>(&v);
}
__device__ __forceinline__ f32x4 mfma16(bf16x8 a, bf16x8 b, f32x4 c) {
    return __builtin_amdgcn_mfma_f32_16x16x32_bf16(a, b, c, 0, 0, 0);
}

// agent-scope relaxed atomics: coherence-point accesses, no cache-wide fences (R4/R5-proven)
__device__ __forceinline__ u64 ld_agent_u64(const u64* p) {
    return __hip_atomic_load(p, __ATOMIC_RELAXED, __HIP_MEMORY_SCOPE_AGENT);
}
__device__ __forceinline__ void st_agent_u64(u64* p, u64 v) {
    __hip_atomic_store(p, v, __ATOMIC_RELAXED, __HIP_MEMORY_SCOPE_AGENT);
}
__device__ __forceinline__ int ld_agent_i32(const int* p) {
    return __hip_atomic_load(p, __ATOMIC_RELAXED, __HIP_MEMORY_SCOPE_AGENT);
}
__device__ __forceinline__ void st_agent_i32(int* p, int v) {
    __hip_atomic_store(p, v, __ATOMIC_RELAXED, __HIP_MEMORY_SCOPE_AGENT);
}

// ---------------- one-time prep ----------------
constexpr int PN0 = 139264;            // W1P ushort8 items
constexpr int PN1 = PN0 + 262144;      // W2P
constexpr int PN2 = PN1 + 4096;        // BIASP f32 items
constexpr int PN3 = PN2 + 131072;      // XPAD ushort8
constexpr int PN4 = PN3 + 32768;       // WD1P ushort8
constexpr int PN5 = PN4 + 32768;       // WD2P
constexpr int PN6 = PN5 + 16384;       // WD3P
constexpr int PN7 = PN6 + 28672;       // zero A1/AN/A2S (16B items)
constexpr int PN8 = PN7 + 256;         // zero BAR (float4)

__global__ __launch_bounds__(256) void prep_kernel(
    const float* __restrict__ seq_in,
    const float* __restrict__ W1, const float* __restrict__ b1,
    const float* __restrict__ W2, const float* __restrict__ b2,
    const float* __restrict__ Wd1, const float* __restrict__ Wd2,
    const float* __restrict__ Wd3, char* __restrict__ ws)
{
    const int idx = blockIdx.x * 256 + threadIdx.x;
    if (idx >= PN8) return;
    if (idx < PN0) {                       // W1P: [np][kk(17)][half][lane][8]
        const int lane = idx & 63; int r = idx >> 6;
        const int half = r & 1; r >>= 1;
        const int kk = r % 17, np = r / 17;
        const int colg = (np*2 + half)*16 + (lane & 15);
        const int oc = (colg & 3)*512 + (colg >> 2);
        const int lg = lane >> 4;
        short v[8];
        #pragma unroll
        for (int j = 0; j < 8; ++j) {
            float x;
            if (kk < 16) x = W1[(size_t)(6 + kk*32 + lg*8 + j) * 2048 + oc];
            else { const int rr = lg*8 + j; x = (rr < 6) ? W1[(size_t)rr * 2048 + oc] : 0.f; }
            v[j] = (short)f2b(x);
        }
        bf16x8* dst = (bf16x8*)((unsigned short*)(ws + OFF_W1P) + ((size_t)(np*17 + kk)*2 + half)*512 + lane*8);
        *dst = *(bf16x8*)v;
    } else if (idx < PN1) {                // W2P: [np][kk(32)][half][lane][8]
        const int i = idx - PN0;
        const int lane = i & 63; int r = i >> 6;
        const int half = r & 1; r >>= 1;
        const int kk = r & 31, np = r >> 5;
        const int colg = (np*2 + half)*16 + (lane & 15);
        const int oc = (colg & 3)*512 + (colg >> 2);
        const int lg = lane >> 4;
        short v[8];
        #pragma unroll
        for (int j = 0; j < 8; ++j)
            v[j] = (short)f2b(W2[(size_t)(kk*32 + lg*8 + j) * 2048 + oc]);
        bf16x8* dst = (bf16x8*)((unsigned short*)(ws + OFF_W2P) + ((size_t)(np*32 + kk)*2 + half)*512 + lane*8);
        *dst = *(bf16x8*)v;
    } else if (idx < PN2) {                // BIASP (gate-permuted)
        const int i = idx - PN1;
        const int layer = i >> 11, colg = i & 2047;
        const float* bb = layer ? b2 : b1;
        ((float*)(ws + OFF_BIASP))[i] = bb[(colg & 3)*512 + (colg >> 2)];
    } else if (idx < PN3) {                // XPAD [t][b][32]
        const int i = idx - PN2;
        const int sub = i & 3, tb = i >> 2;
        const int t = tb >> 6, b = tb & 63;
        short v[8];
        #pragma unroll
        for (int j = 0; j < 8; ++j) {
            const int rr = sub*8 + j;
            v[j] = (short)f2b(rr < 6 ? seq_in[((size_t)b*Tn + t)*6 + rr] : 0.f);
        }
        bf16x8* dst = (bf16x8*)((unsigned short*)(ws + OFF_XPAD) + (size_t)tb*32 + sub*8);
        *dst = *(bf16x8*)v;
    } else if (idx < PN6) {                // WD1P / WD2P / WD3P: [np][kk(16)][lane][8]
        int i; const float* Wd; size_t dsto; int N;
        if (idx < PN4)      { i = idx - PN3; Wd = Wd1; dsto = OFF_WD1P; N = 512; }
        else if (idx < PN5) { i = idx - PN4; Wd = Wd2; dsto = OFF_WD2P; N = 512; }
        else                { i = idx - PN5; Wd = Wd3; dsto = OFF_WD3P; N = 256; }
        const int lane = i & 63; const int r = i >> 6;
        const int kk = r & 15, np = r >> 4;
        const int col = np*16 + (lane & 15);
        const int lg = lane >> 4;
        short v[8];
        #pragma unroll
        for (int j = 0; j < 8; ++j)
            v[j] = (short)f2b(Wd[(size_t)(kk*32 + lg*8 + j) * N + col]);
        bf16x8* dst = (bf16x8*)((unsigned short*)(ws + dsto) + ((size_t)(np*16 + kk)*64 + lane)*8);
        *dst = *(bf16x8*)v;
    } else if (idx < PN7) {                // zero A1+AN+A2S
        const int i = idx - PN6;
        bf16x8 z = {};
        ((bf16x8*)(ws + OFF_A1))[i] = z;
    } else {                               // zero barrier slots
        const int i = idx - PN7;
        ((float4*)(ws + OFF_BAR))[i] = make_float4(0.f, 0.f, 0.f, 0.f);
    }
}

// ---------------- decoupled counter wait ----------------
// lanes 0..15 poll slotsL1 (grp[0..15]) >= tgtA; lanes 16..31 poll slotsL2
// (grp[16..31]) >= tgtB; then block-wide barrier.
__device__ __forceinline__ void wait_grp(const int* grp, int tgtA, int tgtB, int tid)
{
    if (tid < 64) {
        const int tg = (tid < 16) ? tgtA : ((tid < 32) ? tgtB : -2000000000);
        const int* p = grp + (tid & 31);
        int v;
        do { v = (tid < 32) ? ld_agent_i32(p) : 0; } while (!__all(v >= tg));
    }
    __syncthreads();
}

// ---------------- persistent recurrence kernel ----------------
// 128 blocks x 512 threads (8 waves). Blocks 0..63: L1; 64..127: L2.
// mt = vb>>4 (batch 16-row group), ng = vb&15 (col group); wave w owns
// col-tile nt = ng*8+w. L1 and L2 run decoupled pipelines linked by monotone
// counters; nh1 triple-buffered so L1 leads L2 by 1-2 steps.
constexpr int FRAGS = 520;   // ushort stride per kk slot (1040 B)

__global__ __launch_bounds__(512, 2) void persist_kernel(const int* __restrict__ lens,
                                                         char* __restrict__ ws)
{
    __shared__ unsigned short afrag[33 * FRAGS];
    __shared__ float sc[8][16][17];

    const int tid = threadIdx.x;
    const int l = tid & 63, w = tid >> 6;
    const int blk = blockIdx.x;
    const bool isL1 = (blk < 64);
    const int vb = isL1 ? blk : blk - 64;
    const int mt = vb >> 4;
    const int ng = vb & 15;
    const int nt = ng * 8 + w;
    const int np = nt >> 1, half = nt & 1;
    const int lr = l & 15, lg = l >> 4;

    u64* A1u  = (u64*)(ws + OFF_A1);
    u64* ANu  = (u64*)(ws + OFF_AN);
    u64* A2Su = (u64*)(ws + OFF_A2S);
    int* grp  = (int*)(ws + OFF_BAR) + mt * 64;
    const float* biasp = (const float*)(ws + OFF_BIASP);
    unsigned short* h2b = (unsigned short*)(ws + OFF_H2ALL);
    const unsigned short* XP = (const unsigned short*)(ws + OFF_XPAD);

    // ---- private W slice in VGPRs for all 512 steps ----
    bf16x8 wreg[32];
    if (isL1) {
        const unsigned short* Bp = (const unsigned short*)(ws + OFF_W1P)
                                 + ((size_t)(np*17)*2 + half)*512 + l*8;
        #pragma unroll
        for (int kk = 0; kk < 17; ++kk) wreg[kk] = *(const bf16x8*)(Bp + (size_t)kk*1024);
    } else {
        const unsigned short* Bp = (const unsigned short*)(ws + OFF_W2P)
                                 + ((size_t)(np*32)*2 + half)*512 + l*8;
        #pragma unroll
        for (int kk = 0; kk < 32; ++kk) wreg[kk] = *(const bf16x8*)(Bp + (size_t)kk*1024);
    }

    const int myb = mt*16 + lr;
    const int myd = nt*4 + lg;
    const int mylen = lens[myb];
    const float biascol = biasp[(isL1 ? 0 : 2048) + nt*16 + lr];
    float c_reg = 0.f, h_reg = 0.f;

    if (isL1) {
        for (int t = 0; t < Tn; ++t) {
            // need: all L1 published t-1; L2 consumed nh1(t-3) (3-deep buffer)
            wait_grp(grp, t, t - 2, tid);
            // ---- stage h1(t-1) + x(t) ----
            const u64* src = A1u + (size_t)((t+1)&1)*8192;
            #pragma unroll
            for (int it = 0; it < 4; ++it) {
                const int idx = tid + it*512;
                const int r = idx >> 7, g4 = idx & 127;
                u64 v = ld_agent_u64(src + (size_t)(mt*16 + r)*128 + g4);
                *(u64*)(afrag + (g4>>3)*FRAGS + (((g4>>1)&3)*16 + r)*8 + (g4&1)*4) = v;
            }
            if (tid < 64) {
                const int r = tid >> 2, lgg = tid & 3;
                bf16x8 v = *(const bf16x8*)(XP + ((size_t)t*64 + mt*16 + r)*32 + lgg*8);
                *(bf16x8*)(afrag + 16*FRAGS + (lgg*16 + r)*8) = v;
            }
            __syncthreads();

            f32x4 acc = {0.f,0.f,0.f,0.f};
            const unsigned short* ap = afrag + l*8;
            #pragma unroll
            for (int kk = 0; kk < 17; ++kk)
                acc = mfma16(*(const bf16x8*)(ap + kk*FRAGS), wreg[kk], acc);

            #pragma unroll
            for (int i = 0; i < 4; ++i) sc[w][lg*4 + i][lr] = acc[i] + biascol;
            asm volatile("s_waitcnt lgkmcnt(0)" ::: "memory");

            const float gi = sc[w][lr][lg*4+0], gj = sc[w][lr][lg*4+1];
            const float gf = sc[w][lr][lg*4+2], go = sc[w][lr][lg*4+3];
            const float m = (t < mylen) ? 1.f : 0.f;
            const float cnew = c_reg*sigf(gf + 1.f) + sigf(gi)*tanhf(gj);
            c_reg = m*cnew + (1.f - m)*c_reg;
            const float nh = tanhf(cnew)*sigf(go);
            const float hb = m*nh + (1.f - m)*h_reg;
            h_reg = hb;

            const int sv = ((int)f2b(hb) << 16) | (int)f2b(nh);
            const int g0 = __shfl(sv, lr), g1 = __shfl(sv, lr+16),
                      g2 = __shfl(sv, lr+32), g3 = __shfl(sv, lr+48);
            if (lg == 0) {
                u64 nhp = (u64)(unsigned)((g0 & 0xffff) | ((g1 & 0xffff) << 16))
                        | ((u64)(unsigned)((g2 & 0xffff) | ((g3 & 0xffff) << 16)) << 32);
                u64 hbp = (u64)(((unsigned)g0 >> 16) | (((unsigned)g1 >> 16) << 16))
                        | ((u64)(((unsigned)g2 >> 16) | (((unsigned)g3 >> 16) << 16)) << 32);
                st_agent_u64(ANu + (size_t)(t%3)*8192 + (size_t)myb*128 + nt, nhp);
                st_agent_u64(A1u + (size_t)(t&1)*8192 + (size_t)myb*128 + nt, hbp);
            }
            asm volatile("s_waitcnt vmcnt(0)" ::: "memory");
            __syncthreads();
            if (tid == 0) st_agent_i32(grp + ng, t + 1);
        }
    } else {
        for (int s = 0; s < Tn; ++s) {
            // need: L1 published step s (nh1(s) ready); all L2 published s-1
            wait_grp(grp, s + 1, s, tid);
            // ---- stage nh1(s) (K 0..511) + h2(s-1) (K 512..1023) ----
            const u64* srcn = ANu  + (size_t)(s%3)*8192;
            const u64* srch = A2Su + (size_t)((s+1)&1)*8192;
            #pragma unroll
            for (int it = 0; it < 8; ++it) {
                const int idx = tid + it*512;
                const int r = idx >> 8, g4 = idx & 255;
                const u64* p = (g4 < 128) ? (srcn + (size_t)(mt*16 + r)*128 + g4)
                                          : (srch + (size_t)(mt*16 + r)*128 + (g4 - 128));
                u64 v = ld_agent_u64(p);
                *(u64*)(afrag + (g4>>3)*FRAGS + (((g4>>1)&3)*16 + r)*8 + (g4&1)*4) = v;
            }
            __syncthreads();

            f32x4 acc = {0.f,0.f,0.f,0.f};
            const unsigned short* ap = afrag + l*8;
            #pragma unroll
            for (int kk = 0; kk < 32; ++kk)
                acc = mfma16(*(const bf16x8*)(ap + kk*FRAGS), wreg[kk], acc);

            #pragma unroll
            for (int i = 0; i < 4; ++i) sc[w][lg*4 + i][lr] = acc[i] + biascol;
            asm volatile("s_waitcnt lgkmcnt(0)" ::: "memory");

            const float gi = sc[w][lr][lg*4+0], gj = sc[w][lr][lg*4+1];
            const float gf = sc[w][lr][lg*4+2], go = sc[w][lr][lg*4+3];
            const float m = (s < mylen) ? 1.f : 0.f;
            const float cnew = c_reg*sigf(gf + 1.f) + sigf(gi)*tanhf(gj);
            c_reg = m*cnew + (1.f - m)*c_reg;
            const float nh = tanhf(cnew)*sigf(go);
            const float hb = m*nh + (1.f - m)*h_reg;
            h_reg = hb;

            const int sv = (int)f2b(hb);
            const int g0 = __shfl(sv, lr), g1 = __shfl(sv, lr+16),
                      g2 = __shfl(sv, lr+32), g3 = __shfl(sv, lr+48);
            if (lg == 0) {
                u64 hbp = (u64)(unsigned)((g0 & 0xffff) | ((g1 & 0xffff) << 16))
                        | ((u64)(unsigned)((g2 & 0xffff) | ((g3 & 0xffff) << 16)) << 32);
                st_agent_u64(A2Su + (size_t)(s&1)*8192 + (size_t)myb*128 + nt, hbp);
            }
            h2b[((size_t)myb*Tn + s)*512 + myd] = f2b(m*nh);   // cached store (head input)
            asm volatile("s_waitcnt vmcnt(0)" ::: "memory");
            __syncthreads();
            if (tid == 0) st_agent_i32(grp + 16 + ng, s + 1);
        }
    }
}

// ---------------- head GEMM: C = relu(A[M,512]bf16 @ WP + bias) -> bf16 ----------------
// WP frag layout [np][kk][lane][8] (np = N/16 col-tile, kk = K/32). W in VGPRs;
// A-frags loaded straight from global (16B/lane, cacheline-clean).
// grid: (N/64, 256); block 256 thr = 4 waves; wave w -> np = bx*4+w; 8 row-tiles/block.
__global__ __launch_bounds__(256) void hgemm_kernel(
    const unsigned short* __restrict__ A, const unsigned short* __restrict__ WP,
    const float* __restrict__ bias, unsigned short* __restrict__ C, int N)
{
    __shared__ unsigned short tr[4][16][24];
    const int tid = threadIdx.x;
    const int l = tid & 63, w = tid >> 6;
    const int np = blockIdx.x * 4 + w;
    const int colbase = np * 16;
    const int lr = l & 15, lg = l >> 4;

    bf16x8 wfr[16];
    #pragma unroll
    for (int kk = 0; kk < 16; ++kk)
        wfr[kk] = *(const bf16x8*)(WP + ((size_t)(np*16 + kk)*64 + l)*8);
    const float bv = bias[colbase + lr];

    for (int i = 0; i < 8; ++i) {
        const int rt = blockIdx.y * 8 + i;
        const unsigned short* ap = A + (size_t)(rt*16 + lr)*512 + lg*8;
        f32x4 acc = {0.f,0.f,0.f,0.f};
        #pragma unroll
        for (int kk = 0; kk < 16; ++kk)
            acc = mfma16(*(const bf16x8*)(ap + kk*32), wfr[kk], acc);
        #pragma unroll
        for (int j = 0; j < 4; ++j)
            tr[w][lg*4 + j][lr] = f2b(fmaxf(acc[j] + bv, 0.f));
        asm volatile("s_waitcnt lgkmcnt(0)" ::: "memory");
        if (lg == 0) {
            bf16x8 r0 = *(const bf16x8*)&tr[w][lr][0];
            bf16x8 r1 = *(const bf16x8*)&tr[w][lr][8];
            unsigned short* cp = C + (size_t)(rt*16 + lr)*N + colbase;
            *(bf16x8*)cp = r0;
            *(bf16x8*)(cp + 8) = r1;
        }
        asm volatile("s_waitcnt lgkmcnt(0)" ::: "memory");
    }
}

// ---------------- final tiny layer: out = X3[M,256]bf16 @ Wd4 + bd4 (f32) ----------------
__global__ __launch_bounds__(256) void d4_kernel(
    const unsigned short* __restrict__ X3, const float* __restrict__ W,
    const float* __restrict__ bias, float* __restrict__ out)
{
    const int lane = threadIdx.x & 63;
    const int rr = threadIdx.x >> 6;
    const size_t r = (size_t)blockIdx.x * 4 + rr;
    float p0 = 0, p1 = 0, p2 = 0, p3 = 0;
    #pragma unroll
    for (int j = 0; j < 4; ++j) {
        const int k = j * 64 + lane;
        const float x = b2f(X3[r * 256 + k]);
        const float4 wv = *reinterpret_cast<const float4*>(W + (size_t)k * 4);
        p0 += x * wv.x; p1 += x * wv.y; p2 += x * wv.z; p3 += x * wv.w;
    }
    #pragma unroll
    for (int off = 32; off > 0; off >>= 1) {
        p0 += __shfl_down(p0, off); p1 += __shfl_down(p1, off);
        p2 += __shfl_down(p2, off); p3 += __shfl_down(p3, off);
    }
    if (lane == 0) {
        *reinterpret_cast<float4*>(out + r * 4) =
            make_float4(p0 + bias[0], p1 + bias[1], p2 + bias[2], p3 + bias[3]);
    }
}

// ---------------- masked sequence MSE ----------------
__global__ __launch_bounds__(256) void loss_kernel(
    const float* __restrict__ out, const float* __restrict__ tgt,
    const int* __restrict__ lens, float* __restrict__ lossp)
{
    __shared__ float red[256];
    float acc = 0.f;
    for (int idx = threadIdx.x; idx < Bn * Tn; idx += 256) {
        const int b = idx >> 9;
        const float4 o = *reinterpret_cast<const float4*>(out + (size_t)idx * 4);
        const float4 g = *reinterpret_cast<const float4*>(tgt + (size_t)idx * 4);
        const float dx = o.x - g.x, dy = o.y - g.y, dz = o.z - g.z, dw = o.w - g.w;
        const float fm = 0.25f * (dx * dx + dy * dy + dz * dz + dw * dw);
        const float ma = fmaxf(fmaxf(fabsf(g.x), fabsf(g.y)), fmaxf(fabsf(g.z), fabsf(g.w)));
        const float mask = (ma > 0.f) ? 1.f : 0.f;
        acc += fm * mask / ((float)lens[b] * 64.f);
    }
    red[threadIdx.x] = acc;
    __syncthreads();
    for (int st = 128; st > 0; st >>= 1) {
        if (threadIdx.x < st) red[threadIdx.x] += red[threadIdx.x + st];
        __syncthreads();
    }
    if (threadIdx.x == 0) *lossp = red[0];
}

__global__ void sentinel_kernel(float* __restrict__ out, int n)
{
    for (int i = blockIdx.x * 256 + threadIdx.x; i < n; i += gridDim.x * 256)
        out[i] = 1.0e9f;
}

extern "C" void kernel_launch(void* const* d_in, const int* in_sizes, int n_in,
                              void* d_out, int out_size, void* d_ws, size_t ws_size,
                              hipStream_t stream)
{
    const float* seq_in = (const float*)d_in[0];
    const float* tgt    = (const float*)d_in[1];
    const int*   lens   = (const int*)d_in[2];
    const float* W1  = (const float*)d_in[3];
    const float* b1  = (const float*)d_in[4];
    const float* W2  = (const float*)d_in[5];
    const float* b2  = (const float*)d_in[6];
    const float* Wd1 = (const float*)d_in[7];
    const float* bd1 = (const float*)d_in[8];
    const float* Wd2 = (const float*)d_in[9];
    const float* bd2 = (const float*)d_in[10];
    const float* Wd3 = (const float*)d_in[11];
    const float* bd3 = (const float*)d_in[12];
    const float* Wd4 = (const float*)d_in[13];
    const float* bd4 = (const float*)d_in[14];
    float* out = (float*)d_out;
    char* ws = (char*)d_ws;

    if (ws_size < WS_NEED) {
        hipLaunchKernelGGL(sentinel_kernel, dim3(256), dim3(256), 0, stream, out, out_size);
        return;
    }

    hipLaunchKernelGGL(prep_kernel, dim3((PN8 + 255) / 256), dim3(256), 0, stream,
                       seq_in, W1, b1, W2, b2, Wd1, Wd2, Wd3, ws);

    hipLaunchKernelGGL(persist_kernel, dim3(128), dim3(512), 0, stream, lens, ws);

    unsigned short* h2b = (unsigned short*)(ws + OFF_H2ALL);
    unsigned short* X1b = (unsigned short*)(ws + OFF_X1);
    unsigned short* X2b = h2b;   // h2all dead after D1
    unsigned short* X3b = X1b;   // X1 dead after D2
    const unsigned short* WD1P = (const unsigned short*)(ws + OFF_WD1P);
    const unsigned short* WD2P = (const unsigned short*)(ws + OFF_WD2P);
    const unsigned short* WD3P = (const unsigned short*)(ws + OFF_WD3P);

    hipLaunchKernelGGL(hgemm_kernel, dim3(8, 256), dim3(256), 0, stream,
                       h2b, WD1P, bd1, X1b, 512);
    hipLaunchKernelGGL(hgemm_kernel, dim3(8, 256), dim3(256), 0, stream,
                       X1b, WD2P, bd2, X2b, 512);
    hipLaunchKernelGGL(hgemm_kernel, dim3(4, 256), dim3(256), 0, stream,
                       X2b, WD3P, bd3, X3b, 256);
    hipLaunchKernelGGL(d4_kernel, dim3((Bn * Tn) / 4), dim3(256), 0, stream,
                       X3b, Wd4, bd4, out);
    hipLaunchKernelGGL(loss_kernel, dim3(1), dim3(256), 0, stream,
                       out, tgt, lens, out + (size_t)Bn * Tn * 4);
}

// Round 8
// 2902.095 us; speedup vs baseline: 2.4547x; 1.1361x over previous
//
#include <hip/hip_runtime.h>
#include <hip/hip_bf16.h>

// ---------------- problem constants ----------------
constexpr int Bn = 64;
constexpr int Tn = 512;

using bf16x8 = __attribute__((ext_vector_type(8))) short;
using f32x4  = __attribute__((ext_vector_type(4))) float;
typedef unsigned long long u64;

// ---------------- ws layout (byte offsets) ----------------
constexpr size_t OFF_A1    = 0;                       // bf16 [2][64][512] blended h1
constexpr size_t OFF_AN    = OFF_A1  + 131072;        // bf16 [3][64][512] nh1 (3-deep)
constexpr size_t OFF_A2S   = OFF_AN  + 196608;        // bf16 [2][64][512] blended h2
constexpr size_t OFF_BAR   = OFF_A2S + 131072;        // int rep[4][8][32] replicated counters
constexpr size_t OFF_BIASP = OFF_BAR + 4096;          // f32 [2][2048] permuted biases
constexpr size_t OFF_H2ALL = OFF_BIASP + 16384;       // bf16 [32768][512]
constexpr size_t OFF_X1    = OFF_H2ALL + 33554432;    // bf16 [32768][512]
constexpr size_t OFF_XPAD  = OFF_X1 + 33554432;       // bf16 [512][64][32]
constexpr size_t OFF_W1P   = OFF_XPAD + 2097152;      // bf16 [64][17][2][64][8]
constexpr size_t OFF_W2P   = OFF_W1P + 2228224;       // bf16 [64][32][2][64][8]
constexpr size_t OFF_WD1P  = OFF_W2P + 4194304;       // bf16 [32][16][64][8]
constexpr size_t OFF_WD2P  = OFF_WD1P + 524288;       // bf16 [32][16][64][8]
constexpr size_t OFF_WD3P  = OFF_WD2P + 524288;       // bf16 [16][16][64][8]
constexpr size_t OFF_PART  = OFF_WD3P + 262144;       // f32 [8192] loss partials
constexpr size_t WS_NEED   = OFF_PART + 32768;

__device__ __forceinline__ float sigf(float x) { return 1.f / (1.f + expf(-x)); }
__device__ __forceinline__ unsigned short f2b(float x) {
    __hip_bfloat16 h = __float2bfloat16(x);
    return *reinterpret_cast<unsigned short*>(&h);
}
__device__ __forceinline__ float b2f(unsigned short u) {
    unsigned v = ((unsigned)u) << 16;
    return *reinterpret_cast<float*>(&v);
}
__device__ __forceinline__ f32x4 mfma16(bf16x8 a, bf16x8 b, f32x4 c) {
    return __builtin_amdgcn_mfma_f32_16x16x32_bf16(a, b, c, 0, 0, 0);
}

// agent-scope relaxed atomics (R4/R5/R7-proven protocol)
__device__ __forceinline__ u64 ld_agent_u64(const u64* p) {
    return __hip_atomic_load(p, __ATOMIC_RELAXED, __HIP_MEMORY_SCOPE_AGENT);
}
__device__ __forceinline__ void st_agent_u64(u64* p, u64 v) {
    __hip_atomic_store(p, v, __ATOMIC_RELAXED, __HIP_MEMORY_SCOPE_AGENT);
}
__device__ __forceinline__ int ld_agent_i32(const int* p) {
    return __hip_atomic_load(p, __ATOMIC_RELAXED, __HIP_MEMORY_SCOPE_AGENT);
}
__device__ __forceinline__ void st_agent_i32(int* p, int v) {
    __hip_atomic_store(p, v, __ATOMIC_RELAXED, __HIP_MEMORY_SCOPE_AGENT);
}

// ---------------- one-time prep ----------------
constexpr int PN0 = 139264;            // W1P ushort8 items
constexpr int PN1 = PN0 + 262144;      // W2P
constexpr int PN2 = PN1 + 4096;        // BIASP f32 items
constexpr int PN3 = PN2 + 131072;      // XPAD ushort8
constexpr int PN4 = PN3 + 32768;       // WD1P ushort8
constexpr int PN5 = PN4 + 32768;       // WD2P
constexpr int PN6 = PN5 + 16384;       // WD3P
constexpr int PN7 = PN6 + 28672;       // zero A1/AN/A2S (16B items)
constexpr int PN8 = PN7 + 256;         // zero BAR (float4)

__global__ __launch_bounds__(256) void prep_kernel(
    const float* __restrict__ seq_in,
    const float* __restrict__ W1, const float* __restrict__ b1,
    const float* __restrict__ W2, const float* __restrict__ b2,
    const float* __restrict__ Wd1, const float* __restrict__ Wd2,
    const float* __restrict__ Wd3, char* __restrict__ ws)
{
    const int idx = blockIdx.x * 256 + threadIdx.x;
    if (idx >= PN8) return;
    if (idx < PN0) {                       // W1P: [np][kk(17)][half][lane][8]
        const int lane = idx & 63; int r = idx >> 6;
        const int half = r & 1; r >>= 1;
        const int kk = r % 17, np = r / 17;
        const int colg = (np*2 + half)*16 + (lane & 15);
        const int oc = (colg & 3)*512 + (colg >> 2);
        const int lg = lane >> 4;
        short v[8];
        #pragma unroll
        for (int j = 0; j < 8; ++j) {
            float x;
            if (kk < 16) x = W1[(size_t)(6 + kk*32 + lg*8 + j) * 2048 + oc];
            else { const int rr = lg*8 + j; x = (rr < 6) ? W1[(size_t)rr * 2048 + oc] : 0.f; }
            v[j] = (short)f2b(x);
        }
        bf16x8* dst = (bf16x8*)((unsigned short*)(ws + OFF_W1P) + ((size_t)(np*17 + kk)*2 + half)*512 + lane*8);
        *dst = *(bf16x8*)v;
    } else if (idx < PN1) {                // W2P: [np][kk(32)][half][lane][8]
        const int i = idx - PN0;
        const int lane = i & 63; int r = i >> 6;
        const int half = r & 1; r >>= 1;
        const int kk = r & 31, np = r >> 5;
        const int colg = (np*2 + half)*16 + (lane & 15);
        const int oc = (colg & 3)*512 + (colg >> 2);
        const int lg = lane >> 4;
        short v[8];
        #pragma unroll
        for (int j = 0; j < 8; ++j)
            v[j] = (short)f2b(W2[(size_t)(kk*32 + lg*8 + j) * 2048 + oc]);
        bf16x8* dst = (bf16x8*)((unsigned short*)(ws + OFF_W2P) + ((size_t)(np*32 + kk)*2 + half)*512 + lane*8);
        *dst = *(bf16x8*)v;
    } else if (idx < PN2) {                // BIASP (gate-permuted)
        const int i = idx - PN1;
        const int layer = i >> 11, colg = i & 2047;
        const float* bb = layer ? b2 : b1;
        ((float*)(ws + OFF_BIASP))[i] = bb[(colg & 3)*512 + (colg >> 2)];
    } else if (idx < PN3) {                // XPAD [t][b][32]
        const int i = idx - PN2;
        const int sub = i & 3, tb = i >> 2;
        const int t = tb >> 6, b = tb & 63;
        short v[8];
        #pragma unroll
        for (int j = 0; j < 8; ++j) {
            const int rr = sub*8 + j;
            v[j] = (short)f2b(rr < 6 ? seq_in[((size_t)b*Tn + t)*6 + rr] : 0.f);
        }
        bf16x8* dst = (bf16x8*)((unsigned short*)(ws + OFF_XPAD) + (size_t)tb*32 + sub*8);
        *dst = *(bf16x8*)v;
    } else if (idx < PN6) {                // WD1P / WD2P / WD3P: [np][kk(16)][lane][8]
        int i; const float* Wd; size_t dsto; int N;
        if (idx < PN4)      { i = idx - PN3; Wd = Wd1; dsto = OFF_WD1P; N = 512; }
        else if (idx < PN5) { i = idx - PN4; Wd = Wd2; dsto = OFF_WD2P; N = 512; }
        else                { i = idx - PN5; Wd = Wd3; dsto = OFF_WD3P; N = 256; }
        const int lane = i & 63; const int r = i >> 6;
        const int kk = r & 15, np = r >> 4;
        const int col = np*16 + (lane & 15);
        const int lg = lane >> 4;
        short v[8];
        #pragma unroll
        for (int j = 0; j < 8; ++j)
            v[j] = (short)f2b(Wd[(size_t)(kk*32 + lg*8 + j) * N + col]);
        bf16x8* dst = (bf16x8*)((unsigned short*)(ws + dsto) + ((size_t)(np*16 + kk)*64 + lane)*8);
        *dst = *(bf16x8*)v;
    } else if (idx < PN7) {                // zero A1+AN+A2S
        const int i = idx - PN6;
        bf16x8 z = {};
        ((bf16x8*)(ws + OFF_A1))[i] = z;
    } else {                               // zero replicated counters
        const int i = idx - PN7;
        ((float4*)(ws + OFF_BAR))[i] = make_float4(0.f, 0.f, 0.f, 0.f);
    }
}

// ---------------- persistent recurrence kernel ----------------
// 128 blocks x 512 threads (8 waves). Blocks 0..63: L1; 64..127: L2.
// mt = vb>>4 (batch 16-row group), ng = vb&15; wave w owns col-tile nt = ng*8+w.
// Sync: replicated monotone counters rep[4][8][32] (8 replica regions/group,
// producers scatter-publish to all 8; each consumer block polls its region —
// no shared poll line). Progressive gather: each thread's staged u64s share
// one column-quad g4 => one producer; thread polls that producer's slot then
// loads its data; __syncthreads() before MFMA joins the block (collectively
// ALL producer counters are checked => anti-overwrite safety as in R7).
constexpr int FRAGS = 520;   // ushort stride per kk slot (1040 B)

__global__ __launch_bounds__(512, 2) void persist_kernel(const int* __restrict__ lens,
                                                         char* __restrict__ ws)
{
    __shared__ unsigned short afrag[33 * FRAGS];
    __shared__ float sc[8][16][17];

    const int tid = threadIdx.x;
    const int l = tid & 63, w = tid >> 6;
    const int blk = blockIdx.x;
    const bool isL1 = (blk < 64);
    const int vb = isL1 ? blk : blk - 64;
    const int mt = vb >> 4;
    const int ng = vb & 15;
    const int nt = ng * 8 + w;
    const int np = nt >> 1, half = nt & 1;
    const int lr = l & 15, lg = l >> 4;

    u64* A1u  = (u64*)(ws + OFF_A1);
    u64* ANu  = (u64*)(ws + OFF_AN);
    u64* A2Su = (u64*)(ws + OFF_A2S);
    int* rep  = (int*)(ws + OFF_BAR);
    const int rsel = isL1 ? (ng >> 2) : (4 + (ng >> 2));
    const int* reg = rep + (mt*8 + rsel)*32;     // my poll region
    const int slot_self = isL1 ? ng : 16 + ng;
    const float* biasp = (const float*)(ws + OFF_BIASP);
    u64* h2bu = (u64*)(ws + OFF_H2ALL);
    const unsigned short* XP = (const unsigned short*)(ws + OFF_XPAD);

    // ---- private W slice in VGPRs for all 512 steps ----
    bf16x8 wreg[32];
    if (isL1) {
        const unsigned short* Bp = (const unsigned short*)(ws + OFF_W1P)
                                 + ((size_t)(np*17)*2 + half)*512 + l*8;
        #pragma unroll
        for (int kk = 0; kk < 17; ++kk) wreg[kk] = *(const bf16x8*)(Bp + (size_t)kk*1024);
    } else {
        const unsigned short* Bp = (const unsigned short*)(ws + OFF_W2P)
                                 + ((size_t)(np*32)*2 + half)*512 + l*8;
        #pragma unroll
        for (int kk = 0; kk < 32; ++kk) wreg[kk] = *(const bf16x8*)(Bp + (size_t)kk*1024);
    }

    const int myb = mt*16 + lr;
    const int mylen = lens[myb];
    const float biascol = biasp[(isL1 ? 0 : 2048) + nt*16 + lr];
    float c_reg = 0.f, h_reg = 0.f;

    if (isL1) {
        const int g4 = tid & 127;
        const int p  = g4 >> 3;            // my column-quad's producer (L1 peer)
        for (int t = 0; t < Tn; ++t) {
            // x-part staging first (no dependence)
            if (tid < 64) {
                const int r = tid >> 2, lgg = tid & 3;
                bf16x8 v = *(const bf16x8*)(XP + ((size_t)t*64 + mt*16 + r)*32 + lgg*8);
                *(bf16x8*)(afrag + 16*FRAGS + (lgg*16 + r)*8) = v;
            }
            // per-thread wait: my producer published h1(t-1)
            while (ld_agent_i32(reg + p) < t) {}
            // designated threads: L2 side consumed nh1(t-3)  (3-deep buffer)
            if (tid < 16) { while (ld_agent_i32(reg + 16 + tid) < t - 2) {} }
            // progressive stage of my column quad (4 rows)
            const u64* src = A1u + (size_t)((t+1)&1)*8192;
            #pragma unroll
            for (int it = 0; it < 4; ++it) {
                const int r = (tid >> 7) + it*4;
                u64 v = ld_agent_u64(src + (size_t)(mt*16 + r)*128 + g4);
                *(u64*)(afrag + (g4>>3)*FRAGS + (((g4>>1)&3)*16 + r)*8 + (g4&1)*4) = v;
            }
            __syncthreads();

            f32x4 acc = {0.f,0.f,0.f,0.f};
            const unsigned short* ap = afrag + l*8;
            #pragma unroll
            for (int kk = 0; kk < 17; ++kk)
                acc = mfma16(*(const bf16x8*)(ap + kk*FRAGS), wreg[kk], acc);

            #pragma unroll
            for (int i = 0; i < 4; ++i) sc[w][lg*4 + i][lr] = acc[i] + biascol;
            asm volatile("s_waitcnt lgkmcnt(0)" ::: "memory");

            const float gi = sc[w][lr][lg*4+0], gj = sc[w][lr][lg*4+1];
            const float gf = sc[w][lr][lg*4+2], go = sc[w][lr][lg*4+3];
            const float m = (t < mylen) ? 1.f : 0.f;
            const float cnew = c_reg*sigf(gf + 1.f) + sigf(gi)*tanhf(gj);
            c_reg = m*cnew + (1.f - m)*c_reg;
            const float nh = tanhf(cnew)*sigf(go);
            const float hb = m*nh + (1.f - m)*h_reg;
            h_reg = hb;

            const int sv = ((int)f2b(hb) << 16) | (int)f2b(nh);
            const int g0 = __shfl(sv, lr), g1 = __shfl(sv, lr+16),
                      g2 = __shfl(sv, lr+32), g3 = __shfl(sv, lr+48);
            if (lg == 0) {
                u64 nhp = (u64)(unsigned)((g0 & 0xffff) | ((g1 & 0xffff) << 16))
                        | ((u64)(unsigned)((g2 & 0xffff) | ((g3 & 0xffff) << 16)) << 32);
                u64 hbp = (u64)(((unsigned)g0 >> 16) | (((unsigned)g1 >> 16) << 16))
                        | ((u64)(((unsigned)g2 >> 16) | (((unsigned)g3 >> 16) << 16)) << 32);
                st_agent_u64(ANu + (size_t)(t%3)*8192 + (size_t)myb*128 + nt, nhp);
                st_agent_u64(A1u + (size_t)(t&1)*8192 + (size_t)myb*128 + nt, hbp);
            }
            asm volatile("s_waitcnt vmcnt(0)" ::: "memory");
            __syncthreads();
            if (tid < 8) st_agent_i32(rep + (mt*8 + tid)*32 + slot_self, t + 1);
        }
    } else {
        const int g4 = tid & 255;
        const int p  = (g4 < 128) ? (g4 >> 3) : (16 + ((g4 - 128) >> 3));
        for (int s = 0; s < Tn; ++s) {
            const int tg = (g4 < 128) ? (s + 1) : s;   // nh1(s) needs L1 >= s+1; h2(s-1) needs L2 >= s
            while (ld_agent_i32(reg + p) < tg) {}
            const u64* srcn = ANu  + (size_t)(s%3)*8192;
            const u64* srch = A2Su + (size_t)((s+1)&1)*8192;
            #pragma unroll
            for (int it = 0; it < 8; ++it) {
                const int r = (tid >> 8) + it*2;
                const u64* pp = (g4 < 128) ? (srcn + (size_t)(mt*16 + r)*128 + g4)
                                           : (srch + (size_t)(mt*16 + r)*128 + (g4 - 128));
                u64 v = ld_agent_u64(pp);
                *(u64*)(afrag + (g4>>3)*FRAGS + (((g4>>1)&3)*16 + r)*8 + (g4&1)*4) = v;
            }
            __syncthreads();

            f32x4 acc = {0.f,0.f,0.f,0.f};
            const unsigned short* ap = afrag + l*8;
            #pragma unroll
            for (int kk = 0; kk < 32; ++kk)
                acc = mfma16(*(const bf16x8*)(ap + kk*FRAGS), wreg[kk], acc);

            #pragma unroll
            for (int i = 0; i < 4; ++i) sc[w][lg*4 + i][lr] = acc[i] + biascol;
            asm volatile("s_waitcnt lgkmcnt(0)" ::: "memory");

            const float gi = sc[w][lr][lg*4+0], gj = sc[w][lr][lg*4+1];
            const float gf = sc[w][lr][lg*4+2], go = sc[w][lr][lg*4+3];
            const float m = (s < mylen) ? 1.f : 0.f;
            const float cnew = c_reg*sigf(gf + 1.f) + sigf(gi)*tanhf(gj);
            c_reg = m*cnew + (1.f - m)*c_reg;
            const float nh = tanhf(cnew)*sigf(go);
            const float hb = m*nh + (1.f - m)*h_reg;
            h_reg = hb;

            const int sv = ((int)f2b(hb) << 16) | (int)f2b(m*nh);
            const int g0 = __shfl(sv, lr), g1 = __shfl(sv, lr+16),
                      g2 = __shfl(sv, lr+32), g3 = __shfl(sv, lr+48);
            if (lg == 0) {
                u64 hbp = (u64)(((unsigned)g0 >> 16) | (((unsigned)g1 >> 16) << 16))
                        | ((u64)(((unsigned)g2 >> 16) | (((unsigned)g3 >> 16) << 16)) << 32);
                u64 nhp = (u64)(unsigned)((g0 & 0xffff) | ((g1 & 0xffff) << 16))
                        | ((u64)(unsigned)((g2 & 0xffff) | ((g3 & 0xffff) << 16)) << 32);
                st_agent_u64(A2Su + (size_t)(s&1)*8192 + (size_t)myb*128 + nt, hbp);
                h2bu[((size_t)myb*Tn + s)*128 + nt] = nhp;   // cached packed store (head input)
            }
            asm volatile("s_waitcnt vmcnt(0)" ::: "memory");
            __syncthreads();
            if (tid < 8) st_agent_i32(rep + (mt*8 + tid)*32 + slot_self, s + 1);
        }
    }
}

// ---------------- head GEMM: C = relu(A[M,512]bf16 @ WP + bias) -> bf16 ----------------
__global__ __launch_bounds__(256) void hgemm_kernel(
    const unsigned short* __restrict__ A, const unsigned short* __restrict__ WP,
    const float* __restrict__ bias, unsigned short* __restrict__ C, int N)
{
    __shared__ unsigned short tr[4][16][24];
    const int tid = threadIdx.x;
    const int l = tid & 63, w = tid >> 6;
    const int np = blockIdx.x * 4 + w;
    const int colbase = np * 16;
    const int lr = l & 15, lg = l >> 4;

    bf16x8 wfr[16];
    #pragma unroll
    for (int kk = 0; kk < 16; ++kk)
        wfr[kk] = *(const bf16x8*)(WP + ((size_t)(np*16 + kk)*64 + l)*8);
    const float bv = bias[colbase + lr];

    for (int i = 0; i < 8; ++i) {
        const int rt = blockIdx.y * 8 + i;
        const unsigned short* ap = A + (size_t)(rt*16 + lr)*512 + lg*8;
        f32x4 acc = {0.f,0.f,0.f,0.f};
        #pragma unroll
        for (int kk = 0; kk < 16; ++kk)
            acc = mfma16(*(const bf16x8*)(ap + kk*32), wfr[kk], acc);
        #pragma unroll
        for (int j = 0; j < 4; ++j)
            tr[w][lg*4 + j][lr] = f2b(fmaxf(acc[j] + bv, 0.f));
        asm volatile("s_waitcnt lgkmcnt(0)" ::: "memory");
        if (lg == 0) {
            bf16x8 r0 = *(const bf16x8*)&tr[w][lr][0];
            bf16x8 r1 = *(const bf16x8*)&tr[w][lr][8];
            unsigned short* cp = C + (size_t)(rt*16 + lr)*N + colbase;
            *(bf16x8*)cp = r0;
            *(bf16x8*)(cp + 8) = r1;
        }
        asm volatile("s_waitcnt lgkmcnt(0)" ::: "memory");
    }
}

// ---------------- final layer + loss partials ----------------
// block = 4 rows; lane covers k = lane*4..lane*4+3 (one u64 X3 load).
__global__ __launch_bounds__(256) void d4_kernel(
    const unsigned short* __restrict__ X3, const float* __restrict__ W,
    const float* __restrict__ bias, const float* __restrict__ tgt,
    const int* __restrict__ lens, float* __restrict__ out,
    float* __restrict__ partials)
{
    __shared__ float pr[4];
    const int lane = threadIdx.x & 63;
    const int rr = threadIdx.x >> 6;
    const size_t r = (size_t)blockIdx.x * 4 + rr;
    const u64 xv = *(const u64*)(X3 + r * 256 + lane * 4);
    const float x0 = b2f((unsigned short)(xv & 0xffff));
    const float x1 = b2f((unsigned short)((xv >> 16) & 0xffff));
    const float x2 = b2f((unsigned short)((xv >> 32) & 0xffff));
    const float x3 = b2f((unsigned short)((xv >> 48) & 0xffff));
    const float4 w0 = *reinterpret_cast<const float4*>(W + (size_t)(lane*4 + 0) * 4);
    const float4 w1 = *reinterpret_cast<const float4*>(W + (size_t)(lane*4 + 1) * 4);
    const float4 w2 = *reinterpret_cast<const float4*>(W + (size_t)(lane*4 + 2) * 4);
    const float4 w3 = *reinterpret_cast<const float4*>(W + (size_t)(lane*4 + 3) * 4);
    float p0 = x0*w0.x + x1*w1.x + x2*w2.x + x3*w3.x;
    float p1 = x0*w0.y + x1*w1.y + x2*w2.y + x3*w3.y;
    float p2 = x0*w0.z + x1*w1.z + x2*w2.z + x3*w3.z;
    float p3 = x0*w0.w + x1*w1.w + x2*w2.w + x3*w3.w;
    #pragma unroll
    for (int off = 32; off > 0; off >>= 1) {
        p0 += __shfl_down(p0, off); p1 += __shfl_down(p1, off);
        p2 += __shfl_down(p2, off); p3 += __shfl_down(p3, off);
    }
    if (lane == 0) {
        const float o0 = p0 + bias[0], o1 = p1 + bias[1];
        const float o2 = p2 + bias[2], o3 = p3 + bias[3];
        *reinterpret_cast<float4*>(out + r * 4) = make_float4(o0, o1, o2, o3);
        const float4 g = *reinterpret_cast<const float4*>(tgt + r * 4);
        const float dx = o0 - g.x, dy = o1 - g.y, dz = o2 - g.z, dw = o3 - g.w;
        const float fm = 0.25f * (dx*dx + dy*dy + dz*dz + dw*dw);
        const float ma = fmaxf(fmaxf(fabsf(g.x), fabsf(g.y)), fmaxf(fabsf(g.z), fabsf(g.w)));
        const float mask = (ma > 0.f) ? 1.f : 0.f;
        const int b = (int)(r >> 9);
        pr[rr] = fm * mask / ((float)lens[b] * 64.f);
    }
    __syncthreads();
    if (threadIdx.x == 0)
        partials[blockIdx.x] = pr[0] + pr[1] + pr[2] + pr[3];
}

__global__ __launch_bounds__(256) void losssum_kernel(const float* __restrict__ partials,
                                                      float* __restrict__ lossp)
{
    __shared__ float red[256];
    float a = 0.f;
    for (int i = threadIdx.x; i < 8192; i += 256) a += partials[i];
    red[threadIdx.x] = a;
    __syncthreads();
    for (int st = 128; st > 0; st >>= 1) {
        if (threadIdx.x < st) red[threadIdx.x] += red[threadIdx.x + st];
        __syncthreads();
    }
    if (threadIdx.x == 0) *lossp = red[0];
}

__global__ void sentinel_kernel(float* __restrict__ out, int n)
{
    for (int i = blockIdx.x * 256 + threadIdx.x; i < n; i += gridDim.x * 256)
        out[i] = 1.0e9f;
}

extern "C" void kernel_launch(void* const* d_in, const int* in_sizes, int n_in,
                              void* d_out, int out_size, void* d_ws, size_t ws_size,
                              hipStream_t stream)
{
    const float* seq_in = (const float*)d_in[0];
    const float* tgt    = (const float*)d_in[1];
    const int*   lens   = (const int*)d_in[2];
    const float* W1  = (const float*)d_in[3];
    const float* b1  = (const float*)d_in[4];
    const float* W2  = (const float*)d_in[5];
    const float* b2  = (const float*)d_in[6];
    const float* Wd1 = (const float*)d_in[7];
    const float* bd1 = (const float*)d_in[8];
    const float* Wd2 = (const float*)d_in[9];
    const float* bd2 = (const float*)d_in[10];
    const float* Wd3 = (const float*)d_in[11];
    const float* bd3 = (const float*)d_in[12];
    const float* Wd4 = (const float*)d_in[13];
    const float* bd4 = (const float*)d_in[14];
    float* out = (float*)d_out;
    char* ws = (char*)d_ws;

    if (ws_size < WS_NEED) {
        hipLaunchKernelGGL(sentinel_kernel, dim3(256), dim3(256), 0, stream, out, out_size);
        return;
    }

    hipLaunchKernelGGL(prep_kernel, dim3((PN8 + 255) / 256), dim3(256), 0, stream,
                       seq_in, W1, b1, W2, b2, Wd1, Wd2, Wd3, ws);

    hipLaunchKernelGGL(persist_kernel, dim3(128), dim3(512), 0, stream, lens, ws);

    unsigned short* h2b = (unsigned short*)(ws + OFF_H2ALL);
    unsigned short* X1b = (unsigned short*)(ws + OFF_X1);
    unsigned short* X2b = h2b;   // h2all dead after D1
    unsigned short* X3b = X1b;   // X1 dead after D2
    const unsigned short* WD1P = (const unsigned short*)(ws + OFF_WD1P);
    const unsigned short* WD2P = (const unsigned short*)(ws + OFF_WD2P);
    const unsigned short* WD3P = (const unsigned short*)(ws + OFF_WD3P);
    float* partials = (float*)(ws + OFF_PART);

    hipLaunchKernelGGL(hgemm_kernel, dim3(8, 256), dim3(256), 0, stream,
                       h2b, WD1P, bd1, X1b, 512);
    hipLaunchKernelGGL(hgemm_kernel, dim3(8, 256), dim3(256), 0, stream,
                       X1b, WD2P, bd2, X2b, 512);
    hipLaunchKernelGGL(hgemm_kernel, dim3(4, 256), dim3(256), 0, stream,
                       X2b, WD3P, bd3, X3b, 256);
    hipLaunchKernelGGL(d4_kernel, dim3((Bn * Tn) / 4), dim3(256), 0, stream,
                       X3b, Wd4, bd4, tgt, lens, out, partials);
    hipLaunchKernelGGL(losssum_kernel, dim3(1), dim3(256), 0, stream,
                       partials, out + (size_t)Bn * Tn * 4);
}